// Round 9
// baseline (5390.243 us; speedup 1.0000x reference)
//
#include <hip/hip_runtime.h>
#include <math.h>

#define CB 64      // batch
#define CT 1024    // time
#define CCH 12     // channels
#define CD 512     // d_model
#define CL 2       // layers
#define CFFN 2048
#define CFCH 256
#define CNC 5
#define CTOPK 20
#define CEPS 1e-5f

typedef __attribute__((ext_vector_type(8))) short bfrag;
typedef __attribute__((ext_vector_type(4))) float ffrag;

__device__ inline ushort bf16r(float f) {
  unsigned u = __float_as_uint(f);
  unsigned r = (u + 0x7FFFu + ((u >> 16) & 1u)) >> 16;
  return (ushort)r;
}
__device__ inline float bf16f(ushort h) { return __uint_as_float(((unsigned)h) << 16); }

// async 16B global->LDS (lds dest = wave-uniform base + lane*16)
__device__ __forceinline__ void gld16(const ushort* g, ushort* l) {
  __builtin_amdgcn_global_load_lds((__attribute__((address_space(1))) void*)g,
                                   (__attribute__((address_space(3))) void*)l,
                                   16, 0, 0);
}

// ---------------- mean-abs scaler ----------------
__global__ __launch_bounds__(256) void k_scale(const float* __restrict__ x,
                                               float* __restrict__ sc,
                                               float* __restrict__ lg) {
  int b = blockIdx.x, tid = threadIdx.x;
  float acc[CCH];
#pragma unroll
  for (int c = 0; c < CCH; ++c) acc[c] = 0.f;
  const float* xb = x + (size_t)b * CT * CCH;
  for (int t = tid; t < CT; t += 256) {
    const float* row = xb + t * CCH;
#pragma unroll
    for (int c = 0; c < CCH; ++c) acc[c] += fabsf(row[c]);
  }
  __shared__ float red[256][CCH];
#pragma unroll
  for (int c = 0; c < CCH; ++c) red[tid][c] = acc[c];
  __syncthreads();
  for (int off = 128; off > 0; off >>= 1) {
    if (tid < off) {
#pragma unroll
      for (int c = 0; c < CCH; ++c) red[tid][c] += red[tid + off][c];
    }
    __syncthreads();
  }
  if (tid < CCH) {
    float s = fmaxf(red[0][tid] * (1.0f / CT), 1e-10f);
    sc[b * CCH + tid] = s;
    lg[b * CCH + tid] = logf(s);
  }
}

// ---------------- sinusoidal position table (f64, matches np) ----------------
__global__ __launch_bounds__(512) void k_postab(float* __restrict__ pos) {
  int t = blockIdx.x;
  int d = threadIdx.x;
  double v;
  if (d < 256) {
    double w = pow(10000.0, -((double)d) / 256.0);
    v = sin((double)t * w);
  } else {
    double w = pow(10000.0, -((double)(d - 256)) / 256.0);
    v = cos((double)t * w);
  }
  pos[(size_t)t * CD + d] = (float)v;
}

// ---------------- embedding + LN fused; writes fp32 h AND bf16 h2 -------------------
__global__ __launch_bounds__(128) void k_embed(const float* __restrict__ x,
                                               const float* __restrict__ sc,
                                               const float* __restrict__ lg,
                                               const float* __restrict__ W,
                                               const float* __restrict__ postab,
                                               const float* __restrict__ g,
                                               const float* __restrict__ beta,
                                               float* __restrict__ h,
                                               ushort* __restrict__ h2) {
  int row = blockIdx.x;  // local: b*T + t
  int b = row >> 10, t = row & 1023;
  int tid = threadIdx.x;
  __shared__ float xs[CCH], ls[CCH];
  if (tid < CCH) {
    float s = sc[b * CCH + tid];
    xs[tid] = x[(size_t)row * CCH + tid] / s;
    ls[tid] = lg[b * CCH + tid];
  }
  __syncthreads();
  int d0 = tid * 4;
  float4 p = *(const float4*)(postab + (size_t)t * CD + d0);
  float v0 = p.x, v1 = p.y, v2 = p.z, v3 = p.w;
#pragma unroll
  for (int c = 0; c < CCH; ++c) {
    float xc = xs[c], lc = ls[c];
    float4 w0 = *(const float4*)(W + (size_t)c * CD + d0);
    float4 w1 = *(const float4*)(W + (size_t)(24 + c) * CD + d0);
    v0 += xc * w0.x + lc * w1.x;
    v1 += xc * w0.y + lc * w1.y;
    v2 += xc * w0.z + lc * w1.z;
    v3 += xc * w0.w + lc * w1.w;
  }
  float s1 = v0 + v1 + v2 + v3;
  float s2 = v0 * v0 + v1 * v1 + v2 * v2 + v3 * v3;
  for (int off = 32; off > 0; off >>= 1) {
    s1 += __shfl_down(s1, off);
    s2 += __shfl_down(s2, off);
  }
  __shared__ float ws1[2], ws2[2], mv[2];
  int wid = tid >> 6, lane = tid & 63;
  if (lane == 0) { ws1[wid] = s1; ws2[wid] = s2; }
  __syncthreads();
  if (tid == 0) {
    float S1 = ws1[0] + ws1[1], S2 = ws2[0] + ws2[1];
    float mu = S1 * (1.0f / CD);
    float var = S2 * (1.0f / CD) - mu * mu;
    mv[0] = mu;
    mv[1] = 1.0f / sqrtf(var + CEPS);
  }
  __syncthreads();
  float mu = mv[0], ri = mv[1];
  float4 gg = *(const float4*)(g + d0);
  float4 bb = *(const float4*)(beta + d0);
  float4 o;
  o.x = (v0 - mu) * ri * gg.x + bb.x;
  o.y = (v1 - mu) * ri * gg.y + bb.y;
  o.z = (v2 - mu) * ri * gg.z + bb.z;
  o.w = (v3 - mu) * ri * gg.w + bb.w;
  *(float4*)(h + (size_t)row * CD + d0) = o;
  ushort4 hv = {bf16r(o.x), bf16r(o.y), bf16r(o.z), bf16r(o.w)};
  *(ushort4*)(h2 + (size_t)row * CD + d0) = hv;
}

// ---------------- weight convert+transpose: W[K][N] fp32 -> W2[N][K] bf16 -----------
__global__ __launch_bounds__(256) void k_cvtw(const float* __restrict__ W,
                                              ushort* __restrict__ W2,
                                              int K, int N) {
  __shared__ float tile[32][33];
  int tx = threadIdx.x & 31, ty = threadIdx.x >> 5;  // ty 0..7
  int n0 = blockIdx.x * 32, k0 = blockIdx.y * 32;
#pragma unroll
  for (int r = 0; r < 4; ++r)
    tile[ty * 4 + r][tx] = W[(size_t)(k0 + ty * 4 + r) * N + n0 + tx];
  __syncthreads();
#pragma unroll
  for (int r = 0; r < 4; ++r) {
    int nl = ty * 4 + r, kl = tx;
    W2[(size_t)(n0 + nl) * K + k0 + kl] = bf16r(tile[kl][nl]);
  }
}

// ---------------- zero helper ----------------
__global__ __launch_bounds__(256) void k_zero(float* __restrict__ p, int n) {
  int i = blockIdx.x * 256 + threadIdx.x;
  if (i < n) p[i] = 0.f;
}

// ---------------- bf16 MFMA GEMM, 128x128 tile, BK=32, double-buffered pipeline -----
// A: [M][lda] bf16 k-contig rows; W: [N][ldb] bf16 k-contig rows.
// LDS: 2 buffers, row stride 32 ushorts; chunk c of row r stored at pos c^(r&3)
// (global source permuted per lane since gld16 dest is fixed base+lane*16).
// Pipeline: prefetch distance 2; per-iter wait `s_waitcnt vmcnt(4)` (one tile).
// EPI: 0=bias->fp32  1=bias+GELU->bf16  2=bias+residual->fp32
//      5=S diagonal-fold (no C store; Cf = corr, atomic)
//      6=bias->bf16 hi (Cs) + lo for cols<1024 (Cs2) [QKV]
template <int EPI>
__global__ __launch_bounds__(256) void k_gemm3(const ushort* __restrict__ A,
                                               const ushort* __restrict__ W,
                                               const float* __restrict__ bias,
                                               const float* __restrict__ R,
                                               float* __restrict__ Cf,
                                               ushort* __restrict__ Cs,
                                               ushort* __restrict__ Cs2,
                                               int lda, int ldb, int ldc, int K,
                                               size_t aBatch, size_t wBatch) {
  __shared__ ushort AhS[2][128 * 32];
  __shared__ ushort BhS[2][128 * 32];
  int tid = threadIdx.x;
  int n0 = blockIdx.x * 128, m0 = blockIdx.y * 128;
  int z = blockIdx.z;
  int wid = __builtin_amdgcn_readfirstlane(tid >> 6);
  int lane = tid & 63;
  int lr = lane >> 2;                        // 0..15: row within a 16-row gld16 group
  int lc = ((lane & 3) ^ (lr & 3)) * 8;      // swizzled source chunk (ushorts)
  int wm = wid >> 1, wn = wid & 1;
  int mOff = wm * 64, nOff = wn * 64;
  int quad = lane >> 4, l16 = lane & 15;

  const ushort* Az = A + (size_t)z * aBatch;
  const ushort* Wz = W + (size_t)z * wBatch;
  // wave wid stages rows [wid*32, wid*32+32): 2 gld16 for A, 2 for B per tile
  const ushort* pA = Az + (size_t)(m0 + wid * 32 + lr) * lda + lc;
  const ushort* pB = Wz + (size_t)(n0 + wid * 32 + lr) * ldb + lc;
  const int NK = K >> 5;

  ffrag acc[4][4];
#pragma unroll
  for (int i = 0; i < 4; ++i)
#pragma unroll
    for (int j = 0; j < 4; ++j) acc[i][j] = (ffrag)(0.f);

#define ISSUE(t, buf)                                                        \
  {                                                                          \
    int kk = (t) << 5;                                                       \
    ushort* lA = &AhS[buf][(wid * 32) * 32];                                 \
    ushort* lB = &BhS[buf][(wid * 32) * 32];                                 \
    gld16(pA + kk, lA);                                                      \
    gld16(pA + (size_t)16 * lda + kk, lA + 16 * 32);                         \
    gld16(pB + kk, lB);                                                      \
    gld16(pB + (size_t)16 * ldb + kk, lB + 16 * 32);                         \
  }

  ISSUE(0, 0);
  ISSUE(1, 1);
  for (int k = 0; k < NK; ++k) {
    if (k + 1 < NK) {
      asm volatile("s_waitcnt vmcnt(4)\n\ts_barrier" ::: "memory");
    } else {
      asm volatile("s_waitcnt vmcnt(0)\n\ts_barrier" ::: "memory");
    }
    int buf = k & 1;
    bfrag ah[4], bh[4];
#pragma unroll
    for (int i = 0; i < 4; ++i) {
      int row = mOff + i * 16 + l16;
      ah[i] = *(const bfrag*)&AhS[buf][row * 32 + (quad ^ (row & 3)) * 8];
    }
#pragma unroll
    for (int j = 0; j < 4; ++j) {
      int row = nOff + j * 16 + l16;
      bh[j] = *(const bfrag*)&BhS[buf][row * 32 + (quad ^ (row & 3)) * 8];
    }
#pragma unroll
    for (int i = 0; i < 4; ++i)
#pragma unroll
      for (int j = 0; j < 4; ++j)
        acc[i][j] = __builtin_amdgcn_mfma_f32_16x16x32_bf16(ah[i], bh[j], acc[i][j], 0, 0, 0);
    asm volatile("s_waitcnt lgkmcnt(0)\n\ts_barrier" ::: "memory");
    if (k + 2 < NK) ISSUE(k + 2, buf);
  }
#undef ISSUE

  if constexpr (EPI == 5) {
    // diagonal fold: corr[z, (m-n)%T] += acc/512  via LDS bins
    __shared__ float bins[256];
    bins[tid] = 0.f;
    __syncthreads();
    int base = 127 + mOff + quad * 4 - nOff - l16;
#pragma unroll
    for (int dd = -3; dd <= 3; ++dd) {
#pragma unroll
      for (int r = 0; r < 4; ++r) {
        float s = 0.f;
#pragma unroll
        for (int i = 0; i < 4; ++i) {
          int j = i - dd;
          if (j >= 0 && j < 4) s += acc[i][j][r];
        }
        atomicAdd(&bins[base + dd * 16 + r], s);
      }
    }
    __syncthreads();
    if (tid < 255) {
      float v = bins[tid];
      if (v != 0.f) {
        int diag = (m0 - n0 + tid - 127 + 2048) & (CT - 1);
        atomicAdd(&Cf[(size_t)z * CT + diag], v * (1.0f / 512.0f));
      }
    }
  } else {
    // C tile layout: col = lane&15, row = quad*4 + reg (verified R3-R7)
#pragma unroll
    for (int j = 0; j < 4; ++j) {
      int col = n0 + nOff + j * 16 + l16;
      float bcol = bias[col];
#pragma unroll
      for (int i = 0; i < 4; ++i) {
        int rowb = m0 + mOff + i * 16 + quad * 4;
#pragma unroll
        for (int r = 0; r < 4; ++r) {
          int row = rowb + r;
          float vv = acc[i][j][r] + bcol;
          if (EPI == 1) vv = 0.5f * vv * (1.0f + erff(vv * 0.7071067811865475f));
          if (EPI == 2) vv += R[(size_t)row * ldc + col];
          if (EPI == 1) {
            Cs[(size_t)row * ldc + col] = bf16r(vv);
          } else if (EPI == 6) {
            ushort hi = bf16r(vv);
            Cs[(size_t)row * ldc + col] = hi;
            if (col < 1024)
              Cs2[(size_t)row * 1024 + col] = bf16r(vv - bf16f(hi));
          } else {
            Cf[(size_t)row * ldc + col] = vv;
          }
        }
      }
    }
  }
}

// ---------------- top-k (k=20) + softmax, 1024 threads ----------------
__global__ __launch_bounds__(1024) void k_topk(const float* __restrict__ corrb,
                                               float* __restrict__ wts,
                                               int* __restrict__ idxs) {
  int b = blockIdx.x, tid = threadIdx.x;
  float cur = corrb[(size_t)b * CT + tid];
  __shared__ float swv[16];
  __shared__ int swi[16];
  __shared__ float selv[CTOPK];
  __shared__ int seli[CTOPK];
  int wid = tid >> 6, lane = tid & 63;
  for (int k = 0; k < CTOPK; ++k) {
    float bv = cur;
    int bi = tid;
#pragma unroll
    for (int off = 32; off > 0; off >>= 1) {
      float ov = __shfl_down(bv, off);
      int oi = __shfl_down(bi, off);
      if (ov > bv || (ov == bv && oi < bi)) { bv = ov; bi = oi; }
    }
    if (lane == 0) { swv[wid] = bv; swi[wid] = bi; }
    __syncthreads();
    if (tid == 0) {
      float mv = swv[0];
      int mi = swi[0];
      for (int q = 1; q < 16; ++q) {
        if (swv[q] > mv || (swv[q] == mv && swi[q] < mi)) { mv = swv[q]; mi = swi[q]; }
      }
      selv[k] = mv;
      seli[k] = mi;
    }
    __syncthreads();
    if (tid == seli[k]) cur = -INFINITY;
    __syncthreads();
  }
  if (tid == 0) {
    float mx = selv[0], sum = 0.f, e[CTOPK];
    for (int k = 0; k < CTOPK; ++k) {
      e[k] = expf(selv[k] - mx);
      sum += e[k];
    }
    float inv = 1.0f / sum;
    for (int k = 0; k < CTOPK; ++k) {
      wts[b * CTOPK + k] = e[k] * inv;
      idxs[b * CTOPK + k] = seli[k];
    }
  }
}

// ---------------- delay aggregation: bf16 V (strided in qkv) -> bf16 out ------------
// XCD-swizzled so each XCD's L2 holds one batch's V slice at a time.
__global__ __launch_bounds__(128) void k_agg(const ushort* __restrict__ qkv,
                                             const float* __restrict__ wts,
                                             const int* __restrict__ idxs,
                                             ushort* __restrict__ out2) {
  int nb = gridDim.x;
  int blk = blockIdx.x;
  int row = (blk & 7) * (nb >> 3) + (blk >> 3);
  int b = row >> 10, t = row & 1023;
  int d0 = threadIdx.x * 4;
  const ushort* Vb = qkv + (size_t)b * CT * 1536 + 1024;
  float4 acc = {0.f, 0.f, 0.f, 0.f};
#pragma unroll
  for (int k = 0; k < CTOPK; ++k) {
    float w = wts[b * CTOPK + k];
    int r = t + idxs[b * CTOPK + k];
    if (r >= CT) r -= CT;
    ushort4 v = *(const ushort4*)(Vb + (size_t)r * 1536 + d0);
    acc.x += w * bf16f(v.x);
    acc.y += w * bf16f(v.y);
    acc.z += w * bf16f(v.z);
    acc.w += w * bf16f(v.w);
  }
  ushort4 hv = {bf16r(acc.x), bf16r(acc.y), bf16r(acc.z), bf16r(acc.w)};
  *(ushort4*)(out2 + (size_t)row * CD + d0) = hv;
}

// ---------------- LayerNorm (optional residual add) ----------------
template <int ADD>
__global__ __launch_bounds__(128) void k_ln(const float* __restrict__ X,
                                            const float* __restrict__ Rr,
                                            const float* __restrict__ g,
                                            const float* __restrict__ beta,
                                            float* __restrict__ out) {
  int row = blockIdx.x, tid = threadIdx.x;
  int d0 = tid * 4;
  float4 v = *(const float4*)(X + (size_t)row * CD + d0);
  if (ADD) {
    float4 r = *(const float4*)(Rr + (size_t)row * CD + d0);
    v.x += r.x; v.y += r.y; v.z += r.z; v.w += r.w;
  }
  float s1 = v.x + v.y + v.z + v.w;
  float s2 = v.x * v.x + v.y * v.y + v.z * v.z + v.w * v.w;
  for (int off = 32; off > 0; off >>= 1) {
    s1 += __shfl_down(s1, off);
    s2 += __shfl_down(s2, off);
  }
  __shared__ float ws1[2], ws2[2], mv[2];
  int wid = tid >> 6, lane = tid & 63;
  if (lane == 0) { ws1[wid] = s1; ws2[wid] = s2; }
  __syncthreads();
  if (tid == 0) {
    float S1 = ws1[0] + ws1[1], S2 = ws2[0] + ws2[1];
    float mu = S1 * (1.0f / CD);
    float var = S2 * (1.0f / CD) - mu * mu;
    mv[0] = mu;
    mv[1] = 1.0f / sqrtf(var + CEPS);
  }
  __syncthreads();
  float mu = mv[0], ri = mv[1];
  float4 gg = *(const float4*)(g + d0);
  float4 bb = *(const float4*)(beta + d0);
  float4 o;
  o.x = (v.x - mu) * ri * gg.x + bb.x;
  o.y = (v.y - mu) * ri * gg.y + bb.y;
  o.z = (v.z - mu) * ri * gg.z + bb.z;
  o.w = (v.w - mu) * ri * gg.w + bb.w;
  *(float4*)(out + (size_t)row * CD + d0) = o;
}

// ---------------- series decomp: fp32 out + bf16 out; XCD-swizzled ------------------
__global__ __launch_bounds__(128) void k_decomp(const float* __restrict__ X,
                                                float* __restrict__ out,
                                                ushort* __restrict__ out2) {
  int nb = gridDim.x;
  int blk = blockIdx.x;
  int row = (blk & 7) * (nb >> 3) + (blk >> 3);
  int b = row >> 10, t = row & 1023;
  int d0 = threadIdx.x * 4;
  const float* xb = X + (size_t)b * CT * CD + d0;
  float4 s = {0.f, 0.f, 0.f, 0.f};
#pragma unroll
  for (int j = -12; j <= 12; ++j) {
    int tt = t + j;
    tt = tt < 0 ? 0 : (tt > CT - 1 ? CT - 1 : tt);
    float4 v = *(const float4*)(xb + (size_t)tt * CD);
    s.x += v.x; s.y += v.y; s.z += v.z; s.w += v.w;
  }
  float4 xv = *(const float4*)(xb + (size_t)t * CD);
  const float inv = 1.0f / 25.0f;
  float4 o = {xv.x - s.x * inv, xv.y - s.y * inv, xv.z - s.z * inv, xv.w - s.w * inv};
  *(float4*)(out + (size_t)row * CD + d0) = o;
  ushort4 hv = {bf16r(o.x), bf16r(o.y), bf16r(o.z), bf16r(o.w)};
  *(ushort4*)(out2 + (size_t)row * CD + d0) = hv;
}

// ---------------- fused time-mean + classification head ----------------
__global__ __launch_bounds__(512) void k_headm(const float* __restrict__ X,
                                               const float* __restrict__ w1,
                                               const float* __restrict__ b1,
                                               const float* __restrict__ w2,
                                               const float* __restrict__ b2,
                                               float* __restrict__ out) {
  int b = blockIdx.x, tid = threadIdx.x;
  __shared__ float f[CD];
  __shared__ float hid[CFCH];
  const float* xb = X + (size_t)b * CT * CD + tid;
  float acc = 0.f;
  for (int t = 0; t < CT; ++t) acc += xb[(size_t)t * CD];
  f[tid] = acc * (1.0f / CT);
  __syncthreads();
  if (tid < CFCH) {
    float a = b1[tid];
    for (int d = 0; d < CD; ++d) a += f[d] * w1[d * CFCH + tid];
    hid[tid] = fmaxf(a, 0.f);
  }
  __syncthreads();
  if (tid < CNC) {
    float a2 = b2[tid];
    for (int j = 0; j < CFCH; ++j) a2 += hid[j] * w2[j * CNC + tid];
    out[b * CNC + tid] = a2;
  }
}

// =====================================================================================
extern "C" void kernel_launch(void* const* d_in, const int* in_sizes, int n_in,
                              void* d_out, int out_size, void* d_ws, size_t ws_size,
                              hipStream_t stream) {
  const float* x = (const float*)d_in[0];
  const float* emb_w = (const float*)d_in[1];
  const float* emb_g = (const float*)d_in[2];
  const float* emb_b = (const float*)d_in[3];
  const float* attn_w = (const float*)d_in[4];
  const float* attn_b = (const float*)d_in[5];
  const float* ln_g = (const float*)d_in[6];
  const float* ln_bb = (const float*)d_in[7];
  const float* fc1_w = (const float*)d_in[8];
  const float* fc1_b = (const float*)d_in[9];
  const float* fc2_w = (const float*)d_in[10];
  const float* fc2_b = (const float*)d_in[11];
  const float* hw1 = (const float*)d_in[12];
  const float* hb1 = (const float*)d_in[13];
  const float* hw2 = (const float*)d_in[14];
  const float* hb2 = (const float*)d_in[15];
  float* outp = (float*)d_out;

  // per-layer bf16 weights (ushorts): wq,wk,wv (contig => fused QKV), wo, w1, w2
  const size_t WQ = 262144ULL;                         // 512*512
  const size_t LW = 4 * WQ + 1048576ULL + 1048576ULL;  // 3,145,728 ushorts
  const size_t W2TOT = CL * LW;

  const size_t FIXED_B = W2TOT * 2                     // bf16 weights
                         + (size_t)CT * CD * 4         // postab
                         + 2 * (size_t)CB * CCH * 4    // sc,lg
                         + (size_t)CB * CT * 4         // corr
                         + 2 * (size_t)CB * CTOPK * 4  // wts,idxs
                         + (size_t)CB * CD * 4         // slack
                         + 4096;
  // per-b bytes: HP(2MB) + SA(2MB, doubles as Q/K-lo bf16 [T][1024]) + U0(1MB) + U1(3MB)
  const size_t PERB = 2ULL * CT * CD * 4 + (size_t)CT * CD * 2 + 3ULL * CT * CD * 2;
  int Bc = CB;
  while (Bc > 1) {
    if ((size_t)Bc * PERB + FIXED_B <= ws_size) break;
    Bc >>= 1;
  }
  const size_t CHF = (size_t)Bc * CT * CD;

  char* wsp = (char*)d_ws;
  float* P0 = (float*)wsp;     wsp += CHF * 4;
  float* P1 = (float*)wsp;     wsp += CHF * 4;
  ushort* U0 = (ushort*)wsp;   wsp += CHF * 2;       // h2 / agg-out / d2
  ushort* U1 = (ushort*)wsp;   wsp += CHF * 3 * 2;   // qkv hi [Mc][1536] / f2
  ushort* W2b = (ushort*)wsp;  wsp += W2TOT * 2;
  float* postab = (float*)wsp; wsp += (size_t)CT * CD * 4;
  float* scb = (float*)wsp;    wsp += (size_t)CB * CCH * 4;
  float* lgb = (float*)wsp;    wsp += (size_t)CB * CCH * 4;
  float* corrb = (float*)wsp;  wsp += (size_t)CB * CT * 4;
  float* wtb = (float*)wsp;    wsp += (size_t)CB * CTOPK * 4;
  int* idb = (int*)wsp;        wsp += (size_t)CB * CTOPK * 4;

  // ---- convert all weights to transposed bf16 [N][K], once per call ----
  for (int l = 0; l < CL; ++l) {
    ushort* wq2 = W2b + l * LW;      // [1536][512] fused QKV (q,k,v contiguous)
    ushort* wo2 = wq2 + 3 * WQ;
    ushort* w12 = wo2 + WQ;
    ushort* w22 = w12 + 1048576;
    for (int m = 0; m < 4; ++m)
      k_cvtw<<<dim3(CD / 32, CD / 32), 256, 0, stream>>>(
          attn_w + ((size_t)(l * 4 + m)) * CD * CD, wq2 + m * WQ, CD, CD);
    k_cvtw<<<dim3(CFFN / 32, CD / 32), 256, 0, stream>>>(
        fc1_w + (size_t)l * CD * CFFN, w12, CD, CFFN);
    k_cvtw<<<dim3(CD / 32, CFFN / 32), 256, 0, stream>>>(
        fc2_w + (size_t)l * CFFN * CD, w22, CFFN, CD);
  }

  k_scale<<<CB, 256, 0, stream>>>(x, scb, lgb);
  k_postab<<<CT, 512, 0, stream>>>(postab);

  const size_t AE3 = (size_t)CT * 1536;  // qkv-hi ushorts per batch elem
  const size_t AE2 = (size_t)CT * 1024;  // qk-lo ushorts per batch elem

  for (int b0 = 0; b0 < CB; b0 += Bc) {
    const int Mc = Bc * CT;
    const int MH = Mc / 2;

    float* HP = P0;
    float* SA = P1;

    k_embed<<<Mc, 128, 0, stream>>>(x + (size_t)b0 * CT * CCH, scb + b0 * CCH,
                                    lgb + b0 * CCH, emb_w, postab, emb_g, emb_b,
                                    HP, U0);

    for (int l = 0; l < CL; ++l) {
      const float* bqkv = attn_b + (size_t)l * 4 * CD;  // q,k,v biases contiguous
      const float* bo = attn_b + (size_t)(l * 4 + 3) * CD;
      const float* g0 = ln_g + (size_t)(l * 2 + 0) * CD;
      const float* be0 = ln_bb + (size_t)(l * 2 + 0) * CD;
      const float* g1 = ln_g + (size_t)(l * 2 + 1) * CD;
      const float* be1 = ln_bb + (size_t)(l * 2 + 1) * CD;
      const float* B1 = fc1_b + (size_t)l * CFFN;
      const float* B2f = fc2_b + (size_t)l * CD;
      const ushort* wq2 = W2b + l * LW;
      const ushort* wo2 = wq2 + 3 * WQ;
      const ushort* w12 = wo2 + WQ;
      const ushort* w22 = w12 + 1048576;

      // Q/K lo-planes live in the currently-free SA buffer (overwritten by O-proj)
      ushort* U2 = (ushort*)SA;  // [Mc][1024]

      // fused QKV projection -> U1 hi [Mc][1536]; Q,K lo -> U2
      k_gemm3<6><<<dim3(1536 / 128, Mc / 128), 256, 0, stream>>>(
          U0, wq2, bqkv, nullptr, nullptr, U1, U2, CD, CD, 1536, CD, 0, 0);
      // corr = fold(Qhi Khi^T) + fold(Qhi Klo^T) + fold(Qlo Khi^T)  (no S buffer)
      k_zero<<<(Bc * CT + 255) / 256, 256, 0, stream>>>(corrb, Bc * CT);
      k_gemm3<5><<<dim3(CT / 128, CT / 128, Bc), 256, 0, stream>>>(
          U1, U1 + 512, nullptr, nullptr, corrb, nullptr, nullptr,
          1536, 1536, 0, CD, AE3, AE3);
      k_gemm3<5><<<dim3(CT / 128, CT / 128, Bc), 256, 0, stream>>>(
          U1, U2 + 512, nullptr, nullptr, corrb, nullptr, nullptr,
          1536, 1024, 0, CD, AE3, AE2);
      k_gemm3<5><<<dim3(CT / 128, CT / 128, Bc), 256, 0, stream>>>(
          U2, U1 + 512, nullptr, nullptr, corrb, nullptr, nullptr,
          1024, 1536, 0, CD, AE2, AE3);
      k_topk<<<Bc, 1024, 0, stream>>>(corrb, wtb, idb);
      // delay aggregation (V strided inside qkv) -> U0; O proj -> SA (fp32)
      k_agg<<<Mc, 128, 0, stream>>>(U1, wtb, idb, U0);
      k_gemm3<0><<<dim3(CD / 128, Mc / 128), 256, 0, stream>>>(
          U0, wo2, bo, nullptr, SA, nullptr, nullptr, CD, CD, CD, CD, 0, 0);
      // residual + LN -> HP; decomp -> SA (fp32 res) + U0 (bf16 d2)
      k_ln<1><<<Mc, 128, 0, stream>>>(HP, SA, g0, be0, HP);
      k_decomp<<<Mc, 128, 0, stream>>>(HP, SA, U0);
      // FFN in two M-halves: FC1 (GELU -> bf16 f2=U1), FC2 (+residual) -> HP
      for (int mh = 0; mh < 2; ++mh) {
        const ushort* inA = U0 + (size_t)mh * MH * CD;
        const float* res = SA + (size_t)mh * MH * CD;
        float* outc = HP + (size_t)mh * MH * CD;
        k_gemm3<1><<<dim3(CFFN / 128, MH / 128), 256, 0, stream>>>(
            inA, w12, B1, nullptr, nullptr, U1, nullptr, CD, CD, CFFN, CD, 0, 0);
        k_gemm3<2><<<dim3(CD / 128, MH / 128), 256, 0, stream>>>(
            U1, w22, B2f, res, outc, nullptr, nullptr, CFFN, CFFN, CD, CFFN, 0, 0);
      }
      // LN -> HP; decomp -> SA (next h fp32) + U0 (next h bf16); swap
      k_ln<0><<<Mc, 128, 0, stream>>>(HP, nullptr, g1, be1, HP);
      k_decomp<<<Mc, 128, 0, stream>>>(HP, SA, U0);
      float* t = HP;
      HP = SA;
      SA = t;
    }

    k_headm<<<Bc, 512, 0, stream>>>(HP, hw1, hb1, hw2, hb2, outp + (size_t)b0 * CNC);
  }
}

// Round 10
// 3943.884 us; speedup vs baseline: 1.3667x; 1.3667x over previous
//
#include <hip/hip_runtime.h>
#include <math.h>

#define CB 64      // batch
#define CT 1024    // time
#define CCH 12     // channels
#define CD 512     // d_model
#define CL 2       // layers
#define CFFN 2048
#define CFCH 256
#define CNC 5
#define CTOPK 20
#define CEPS 1e-5f

typedef __attribute__((ext_vector_type(8))) short bfrag;
typedef __attribute__((ext_vector_type(4))) float ffrag;

__device__ inline ushort bf16r(float f) {
  unsigned u = __float_as_uint(f);
  unsigned r = (u + 0x7FFFu + ((u >> 16) & 1u)) >> 16;
  return (ushort)r;
}
__device__ inline float bf16f(ushort h) { return __uint_as_float(((unsigned)h) << 16); }

// async 16B global->LDS (lds dest = wave-uniform base + lane*16)
__device__ __forceinline__ void gld16(const ushort* g, ushort* l) {
  __builtin_amdgcn_global_load_lds((__attribute__((address_space(1))) void*)g,
                                   (__attribute__((address_space(3))) void*)l,
                                   16, 0, 0);
}

// ---------------- mean-abs scaler ----------------
__global__ __launch_bounds__(256) void k_scale(const float* __restrict__ x,
                                               float* __restrict__ sc,
                                               float* __restrict__ lg) {
  int b = blockIdx.x, tid = threadIdx.x;
  float acc[CCH];
#pragma unroll
  for (int c = 0; c < CCH; ++c) acc[c] = 0.f;
  const float* xb = x + (size_t)b * CT * CCH;
  for (int t = tid; t < CT; t += 256) {
    const float* row = xb + t * CCH;
#pragma unroll
    for (int c = 0; c < CCH; ++c) acc[c] += fabsf(row[c]);
  }
  __shared__ float red[256][CCH];
#pragma unroll
  for (int c = 0; c < CCH; ++c) red[tid][c] = acc[c];
  __syncthreads();
  for (int off = 128; off > 0; off >>= 1) {
    if (tid < off) {
#pragma unroll
      for (int c = 0; c < CCH; ++c) red[tid][c] += red[tid + off][c];
    }
    __syncthreads();
  }
  if (tid < CCH) {
    float s = fmaxf(red[0][tid] * (1.0f / CT), 1e-10f);
    sc[b * CCH + tid] = s;
    lg[b * CCH + tid] = logf(s);
  }
}

// ---------------- sinusoidal position table (f64, matches np) ----------------
__global__ __launch_bounds__(512) void k_postab(float* __restrict__ pos) {
  int t = blockIdx.x;
  int d = threadIdx.x;
  double v;
  if (d < 256) {
    double w = pow(10000.0, -((double)d) / 256.0);
    v = sin((double)t * w);
  } else {
    double w = pow(10000.0, -((double)(d - 256)) / 256.0);
    v = cos((double)t * w);
  }
  pos[(size_t)t * CD + d] = (float)v;
}

// ---------------- embedding + LN fused; writes fp32 h AND bf16 h2 -------------------
__global__ __launch_bounds__(128) void k_embed(const float* __restrict__ x,
                                               const float* __restrict__ sc,
                                               const float* __restrict__ lg,
                                               const float* __restrict__ W,
                                               const float* __restrict__ postab,
                                               const float* __restrict__ g,
                                               const float* __restrict__ beta,
                                               float* __restrict__ h,
                                               ushort* __restrict__ h2) {
  int row = blockIdx.x;  // local: b*T + t
  int b = row >> 10, t = row & 1023;
  int tid = threadIdx.x;
  __shared__ float xs[CCH], ls[CCH];
  if (tid < CCH) {
    float s = sc[b * CCH + tid];
    xs[tid] = x[(size_t)row * CCH + tid] / s;
    ls[tid] = lg[b * CCH + tid];
  }
  __syncthreads();
  int d0 = tid * 4;
  float4 p = *(const float4*)(postab + (size_t)t * CD + d0);
  float v0 = p.x, v1 = p.y, v2 = p.z, v3 = p.w;
#pragma unroll
  for (int c = 0; c < CCH; ++c) {
    float xc = xs[c], lc = ls[c];
    float4 w0 = *(const float4*)(W + (size_t)c * CD + d0);
    float4 w1 = *(const float4*)(W + (size_t)(24 + c) * CD + d0);
    v0 += xc * w0.x + lc * w1.x;
    v1 += xc * w0.y + lc * w1.y;
    v2 += xc * w0.z + lc * w1.z;
    v3 += xc * w0.w + lc * w1.w;
  }
  float s1 = v0 + v1 + v2 + v3;
  float s2 = v0 * v0 + v1 * v1 + v2 * v2 + v3 * v3;
  for (int off = 32; off > 0; off >>= 1) {
    s1 += __shfl_down(s1, off);
    s2 += __shfl_down(s2, off);
  }
  __shared__ float ws1[2], ws2[2], mv[2];
  int wid = tid >> 6, lane = tid & 63;
  if (lane == 0) { ws1[wid] = s1; ws2[wid] = s2; }
  __syncthreads();
  if (tid == 0) {
    float S1 = ws1[0] + ws1[1], S2 = ws2[0] + ws2[1];
    float mu = S1 * (1.0f / CD);
    float var = S2 * (1.0f / CD) - mu * mu;
    mv[0] = mu;
    mv[1] = 1.0f / sqrtf(var + CEPS);
  }
  __syncthreads();
  float mu = mv[0], ri = mv[1];
  float4 gg = *(const float4*)(g + d0);
  float4 bb = *(const float4*)(beta + d0);
  float4 o;
  o.x = (v0 - mu) * ri * gg.x + bb.x;
  o.y = (v1 - mu) * ri * gg.y + bb.y;
  o.z = (v2 - mu) * ri * gg.z + bb.z;
  o.w = (v3 - mu) * ri * gg.w + bb.w;
  *(float4*)(h + (size_t)row * CD + d0) = o;
  ushort4 hv = {bf16r(o.x), bf16r(o.y), bf16r(o.z), bf16r(o.w)};
  *(ushort4*)(h2 + (size_t)row * CD + d0) = hv;
}

// ---------------- weight convert+transpose: W[K][N] fp32 -> W2[N][K] bf16 -----------
__global__ __launch_bounds__(256) void k_cvtw(const float* __restrict__ W,
                                              ushort* __restrict__ W2,
                                              int K, int N) {
  __shared__ float tile[32][33];
  int tx = threadIdx.x & 31, ty = threadIdx.x >> 5;  // ty 0..7
  int n0 = blockIdx.x * 32, k0 = blockIdx.y * 32;
#pragma unroll
  for (int r = 0; r < 4; ++r)
    tile[ty * 4 + r][tx] = W[(size_t)(k0 + ty * 4 + r) * N + n0 + tx];
  __syncthreads();
#pragma unroll
  for (int r = 0; r < 4; ++r) {
    int nl = ty * 4 + r, kl = tx;
    W2[(size_t)(n0 + nl) * K + k0 + kl] = bf16r(tile[kl][nl]);
  }
}

// ---------------- zero helper ----------------
__global__ __launch_bounds__(256) void k_zero(float* __restrict__ p, int n) {
  int i = blockIdx.x * 256 + threadIdx.x;
  if (i < n) p[i] = 0.f;
}

// ---------------- bf16 MFMA GEMM, 128x128 tile, BK=32, double-buffered pipeline -----
// A: [M][lda] bf16 k-contig rows; W: [N][ldb] bf16 k-contig rows.
// Pipeline: prefetch distance 2; per-iter wait `s_waitcnt vmcnt(4)` (own tile's
// loads) + s_barrier (all waves' tile done). Verified correct R8/R9.
// EPI: 0=bias->fp32  1=bias+GELU->bf16  2=bias+residual->fp32
//      6=bias->bf16 hi (Cs, ldc) + lo for cols<1024 (Cs2, ld 1024) [QKV]
template <int EPI>
__global__ __launch_bounds__(256) void k_gemm3(const ushort* __restrict__ A,
                                               const ushort* __restrict__ W,
                                               const float* __restrict__ bias,
                                               const float* __restrict__ R,
                                               float* __restrict__ Cf,
                                               ushort* __restrict__ Cs,
                                               ushort* __restrict__ Cs2,
                                               int lda, int ldb, int ldc, int K) {
  __shared__ ushort AhS[2][128 * 32];
  __shared__ ushort BhS[2][128 * 32];
  int tid = threadIdx.x;
  int n0 = blockIdx.x * 128, m0 = blockIdx.y * 128;
  int wid = __builtin_amdgcn_readfirstlane(tid >> 6);
  int lane = tid & 63;
  int lr = lane >> 2;                        // 0..15: row within a 16-row gld16 group
  int lc = ((lane & 3) ^ (lr & 3)) * 8;      // swizzled source chunk (ushorts)
  int wm = wid >> 1, wn = wid & 1;
  int mOff = wm * 64, nOff = wn * 64;
  int quad = lane >> 4, l16 = lane & 15;

  const ushort* pA = A + (size_t)(m0 + wid * 32 + lr) * lda + lc;
  const ushort* pB = W + (size_t)(n0 + wid * 32 + lr) * ldb + lc;
  const int NK = K >> 5;

  ffrag acc[4][4];
#pragma unroll
  for (int i = 0; i < 4; ++i)
#pragma unroll
    for (int j = 0; j < 4; ++j) acc[i][j] = (ffrag)(0.f);

#define ISSUE(t, buf)                                                        \
  {                                                                          \
    int kk = (t) << 5;                                                       \
    ushort* lA = &AhS[buf][(wid * 32) * 32];                                 \
    ushort* lB = &BhS[buf][(wid * 32) * 32];                                 \
    gld16(pA + kk, lA);                                                      \
    gld16(pA + (size_t)16 * lda + kk, lA + 16 * 32);                         \
    gld16(pB + kk, lB);                                                      \
    gld16(pB + (size_t)16 * ldb + kk, lB + 16 * 32);                         \
  }

  ISSUE(0, 0);
  ISSUE(1, 1);
  for (int k = 0; k < NK; ++k) {
    if (k + 1 < NK) {
      asm volatile("s_waitcnt vmcnt(4)\n\ts_barrier" ::: "memory");
    } else {
      asm volatile("s_waitcnt vmcnt(0)\n\ts_barrier" ::: "memory");
    }
    int buf = k & 1;
    bfrag ah[4], bh[4];
#pragma unroll
    for (int i = 0; i < 4; ++i) {
      int row = mOff + i * 16 + l16;
      ah[i] = *(const bfrag*)&AhS[buf][row * 32 + (quad ^ (row & 3)) * 8];
    }
#pragma unroll
    for (int j = 0; j < 4; ++j) {
      int row = nOff + j * 16 + l16;
      bh[j] = *(const bfrag*)&BhS[buf][row * 32 + (quad ^ (row & 3)) * 8];
    }
#pragma unroll
    for (int i = 0; i < 4; ++i)
#pragma unroll
      for (int j = 0; j < 4; ++j)
        acc[i][j] = __builtin_amdgcn_mfma_f32_16x16x32_bf16(ah[i], bh[j], acc[i][j], 0, 0, 0);
    asm volatile("s_barrier" ::: "memory");
    if (k + 2 < NK) ISSUE(k + 2, buf);
  }
#undef ISSUE

  // C tile layout: col = lane&15, row = quad*4 + reg (verified R3-R9)
#pragma unroll
  for (int j = 0; j < 4; ++j) {
    int col = n0 + nOff + j * 16 + l16;
    float bcol = bias[col];
#pragma unroll
    for (int i = 0; i < 4; ++i) {
      int rowb = m0 + mOff + i * 16 + quad * 4;
#pragma unroll
      for (int r = 0; r < 4; ++r) {
        int row = rowb + r;
        float vv = acc[i][j][r] + bcol;
        if (EPI == 1) vv = 0.5f * vv * (1.0f + erff(vv * 0.7071067811865475f));
        if (EPI == 2) vv += R[(size_t)row * ldc + col];
        if (EPI == 1) {
          Cs[(size_t)row * ldc + col] = bf16r(vv);
        } else if (EPI == 6) {
          ushort hi = bf16r(vv);
          Cs[(size_t)row * ldc + col] = hi;
          if (col < 1024)
            Cs2[(size_t)row * 1024 + col] = bf16r(vv - bf16f(hi));
        } else {
          Cf[(size_t)row * ldc + col] = vv;
        }
      }
    }
  }
}

// ---------------- fused 3-term correlation fold ------------------------------------
// corr[z,(m-n)%T] += (1/512) * sum_d [Qhi*Khi + Qhi*Klo + Qlo*Khi]
// Qhi/Khi rows in U1 (ld 2048, K at col 512); Qlo/Klo in U2 (ld 1024, Klo at 512).
__global__ __launch_bounds__(256) void k_corr3(const ushort* __restrict__ Hi,
                                               const ushort* __restrict__ Lo,
                                               float* __restrict__ corrb) {
  __shared__ ushort AhS[2][128 * 32], AlS[2][128 * 32];
  __shared__ ushort BhS[2][128 * 32], BlS[2][128 * 32];
  int tid = threadIdx.x;
  int n0 = blockIdx.x * 128, m0 = blockIdx.y * 128;
  int z = blockIdx.z;
  int wid = __builtin_amdgcn_readfirstlane(tid >> 6);
  int lane = tid & 63;
  int lr = lane >> 2;
  int lc = ((lane & 3) ^ (lr & 3)) * 8;
  int wm = wid >> 1, wn = wid & 1;
  int mOff = wm * 64, nOff = wn * 64;
  int quad = lane >> 4, l16 = lane & 15;

  const ushort* Hz = Hi + (size_t)z * CT * 2048;
  const ushort* Lz = Lo + (size_t)z * CT * 1024;
  const ushort* pAh = Hz + (size_t)(m0 + wid * 32 + lr) * 2048 + lc;
  const ushort* pAl = Lz + (size_t)(m0 + wid * 32 + lr) * 1024 + lc;
  const ushort* pBh = Hz + 512 + (size_t)(n0 + wid * 32 + lr) * 2048 + lc;
  const ushort* pBl = Lz + 512 + (size_t)(n0 + wid * 32 + lr) * 1024 + lc;
  const int NK = 16;  // 512/32

  ffrag acc[4][4];
#pragma unroll
  for (int i = 0; i < 4; ++i)
#pragma unroll
    for (int j = 0; j < 4; ++j) acc[i][j] = (ffrag)(0.f);

#define ISSUE3(t, buf)                                                       \
  {                                                                          \
    int kk = (t) << 5;                                                       \
    int base = (wid * 32) * 32;                                              \
    gld16(pAh + kk, &AhS[buf][base]);                                        \
    gld16(pAh + (size_t)16 * 2048 + kk, &AhS[buf][base + 16 * 32]);          \
    gld16(pAl + kk, &AlS[buf][base]);                                        \
    gld16(pAl + (size_t)16 * 1024 + kk, &AlS[buf][base + 16 * 32]);          \
    gld16(pBh + kk, &BhS[buf][base]);                                        \
    gld16(pBh + (size_t)16 * 2048 + kk, &BhS[buf][base + 16 * 32]);          \
    gld16(pBl + kk, &BlS[buf][base]);                                        \
    gld16(pBl + (size_t)16 * 1024 + kk, &BlS[buf][base + 16 * 32]);          \
  }

  ISSUE3(0, 0);
  ISSUE3(1, 1);
  for (int k = 0; k < NK; ++k) {
    if (k + 1 < NK) {
      asm volatile("s_waitcnt vmcnt(8)\n\ts_barrier" ::: "memory");
    } else {
      asm volatile("s_waitcnt vmcnt(0)\n\ts_barrier" ::: "memory");
    }
    int buf = k & 1;
    bfrag ah[4], al[4], bh[4], bl[4];
#pragma unroll
    for (int i = 0; i < 4; ++i) {
      int row = mOff + i * 16 + l16;
      int off = row * 32 + (quad ^ (row & 3)) * 8;
      ah[i] = *(const bfrag*)&AhS[buf][off];
      al[i] = *(const bfrag*)&AlS[buf][off];
    }
#pragma unroll
    for (int j = 0; j < 4; ++j) {
      int row = nOff + j * 16 + l16;
      int off = row * 32 + (quad ^ (row & 3)) * 8;
      bh[j] = *(const bfrag*)&BhS[buf][off];
      bl[j] = *(const bfrag*)&BlS[buf][off];
    }
#pragma unroll
    for (int i = 0; i < 4; ++i)
#pragma unroll
      for (int j = 0; j < 4; ++j) {
        acc[i][j] = __builtin_amdgcn_mfma_f32_16x16x32_bf16(ah[i], bh[j], acc[i][j], 0, 0, 0);
        acc[i][j] = __builtin_amdgcn_mfma_f32_16x16x32_bf16(ah[i], bl[j], acc[i][j], 0, 0, 0);
        acc[i][j] = __builtin_amdgcn_mfma_f32_16x16x32_bf16(al[i], bh[j], acc[i][j], 0, 0, 0);
      }
    asm volatile("s_barrier" ::: "memory");
    if (k + 2 < NK) ISSUE3(k + 2, buf);
  }
#undef ISSUE3

  // diagonal fold via LDS bins (reuses AhS space — loop is done)
  __shared__ float bins[256];
  bins[tid] = 0.f;
  __syncthreads();
  int base = 127 + mOff + quad * 4 - nOff - l16;
#pragma unroll
  for (int dd = -3; dd <= 3; ++dd) {
#pragma unroll
    for (int r = 0; r < 4; ++r) {
      float s = 0.f;
#pragma unroll
      for (int i = 0; i < 4; ++i) {
        int j = i - dd;
        if (j >= 0 && j < 4) s += acc[i][j][r];
      }
      atomicAdd(&bins[base + dd * 16 + r], s);
    }
  }
  __syncthreads();
  if (tid < 255) {
    float v = bins[tid];
    if (v != 0.f) {
      int diag = (m0 - n0 + tid - 127 + 2048) & (CT - 1);
      atomicAdd(&corrb[(size_t)z * CT + diag], v * (1.0f / 512.0f));
    }
  }
}

// ---------------- top-k (k=20) + softmax, 1024 threads ----------------
__global__ __launch_bounds__(1024) void k_topk(const float* __restrict__ corrb,
                                               float* __restrict__ wts,
                                               int* __restrict__ idxs) {
  int b = blockIdx.x, tid = threadIdx.x;
  float cur = corrb[(size_t)b * CT + tid];
  __shared__ float swv[16];
  __shared__ int swi[16];
  __shared__ float selv[CTOPK];
  __shared__ int seli[CTOPK];
  int wid = tid >> 6, lane = tid & 63;
  for (int k = 0; k < CTOPK; ++k) {
    float bv = cur;
    int bi = tid;
#pragma unroll
    for (int off = 32; off > 0; off >>= 1) {
      float ov = __shfl_down(bv, off);
      int oi = __shfl_down(bi, off);
      if (ov > bv || (ov == bv && oi < bi)) { bv = ov; bi = oi; }
    }
    if (lane == 0) { swv[wid] = bv; swi[wid] = bi; }
    __syncthreads();
    if (tid == 0) {
      float mv = swv[0];
      int mi = swi[0];
      for (int q = 1; q < 16; ++q) {
        if (swv[q] > mv || (swv[q] == mv && swi[q] < mi)) { mv = swv[q]; mi = swi[q]; }
      }
      selv[k] = mv;
      seli[k] = mi;
    }
    __syncthreads();
    if (tid == seli[k]) cur = -INFINITY;
    __syncthreads();
  }
  if (tid == 0) {
    float mx = selv[0], sum = 0.f, e[CTOPK];
    for (int k = 0; k < CTOPK; ++k) {
      e[k] = expf(selv[k] - mx);
      sum += e[k];
    }
    float inv = 1.0f / sum;
    for (int k = 0; k < CTOPK; ++k) {
      wts[b * CTOPK + k] = e[k] * inv;
      idxs[b * CTOPK + k] = seli[k];
    }
  }
}

// ---------------- delay aggregation: bf16 V (cols 1024.. in U1, ld 2048) ------------
__global__ __launch_bounds__(128) void k_agg(const ushort* __restrict__ qkv,
                                             const float* __restrict__ wts,
                                             const int* __restrict__ idxs,
                                             ushort* __restrict__ out2) {
  int nb = gridDim.x;
  int blk = blockIdx.x;
  int row = (blk & 7) * (nb >> 3) + (blk >> 3);
  int b = row >> 10, t = row & 1023;
  int d0 = threadIdx.x * 4;
  const ushort* Vb = qkv + (size_t)b * CT * 2048 + 1024;
  float4 acc = {0.f, 0.f, 0.f, 0.f};
#pragma unroll
  for (int k = 0; k < CTOPK; ++k) {
    float w = wts[b * CTOPK + k];
    int r = t + idxs[b * CTOPK + k];
    if (r >= CT) r -= CT;
    ushort4 v = *(const ushort4*)(Vb + (size_t)r * 2048 + d0);
    acc.x += w * bf16f(v.x);
    acc.y += w * bf16f(v.y);
    acc.z += w * bf16f(v.z);
    acc.w += w * bf16f(v.w);
  }
  ushort4 hv = {bf16r(acc.x), bf16r(acc.y), bf16r(acc.z), bf16r(acc.w)};
  *(ushort4*)(out2 + (size_t)row * CD + d0) = hv;
}

// ---------------- LayerNorm (optional residual add) ----------------
template <int ADD>
__global__ __launch_bounds__(128) void k_ln(const float* __restrict__ X,
                                            const float* __restrict__ Rr,
                                            const float* __restrict__ g,
                                            const float* __restrict__ beta,
                                            float* __restrict__ out) {
  int row = blockIdx.x, tid = threadIdx.x;
  int d0 = tid * 4;
  float4 v = *(const float4*)(X + (size_t)row * CD + d0);
  if (ADD) {
    float4 r = *(const float4*)(Rr + (size_t)row * CD + d0);
    v.x += r.x; v.y += r.y; v.z += r.z; v.w += r.w;
  }
  float s1 = v.x + v.y + v.z + v.w;
  float s2 = v.x * v.x + v.y * v.y + v.z * v.z + v.w * v.w;
  for (int off = 32; off > 0; off >>= 1) {
    s1 += __shfl_down(s1, off);
    s2 += __shfl_down(s2, off);
  }
  __shared__ float ws1[2], ws2[2], mv[2];
  int wid = tid >> 6, lane = tid & 63;
  if (lane == 0) { ws1[wid] = s1; ws2[wid] = s2; }
  __syncthreads();
  if (tid == 0) {
    float S1 = ws1[0] + ws1[1], S2 = ws2[0] + ws2[1];
    float mu = S1 * (1.0f / CD);
    float var = S2 * (1.0f / CD) - mu * mu;
    mv[0] = mu;
    mv[1] = 1.0f / sqrtf(var + CEPS);
  }
  __syncthreads();
  float mu = mv[0], ri = mv[1];
  float4 gg = *(const float4*)(g + d0);
  float4 bb = *(const float4*)(beta + d0);
  float4 o;
  o.x = (v.x - mu) * ri * gg.x + bb.x;
  o.y = (v.y - mu) * ri * gg.y + bb.y;
  o.z = (v.z - mu) * ri * gg.z + bb.z;
  o.w = (v.w - mu) * ri * gg.w + bb.w;
  *(float4*)(out + (size_t)row * CD + d0) = o;
}

// ---------------- series decomp: fp32 out + bf16 out; XCD-swizzled ------------------
__global__ __launch_bounds__(128) void k_decomp(const float* __restrict__ X,
                                                float* __restrict__ out,
                                                ushort* __restrict__ out2) {
  int nb = gridDim.x;
  int blk = blockIdx.x;
  int row = (blk & 7) * (nb >> 3) + (blk >> 3);
  int b = row >> 10, t = row & 1023;
  int d0 = threadIdx.x * 4;
  const float* xb = X + (size_t)b * CT * CD + d0;
  float4 s = {0.f, 0.f, 0.f, 0.f};
#pragma unroll
  for (int j = -12; j <= 12; ++j) {
    int tt = t + j;
    tt = tt < 0 ? 0 : (tt > CT - 1 ? CT - 1 : tt);
    float4 v = *(const float4*)(xb + (size_t)tt * CD);
    s.x += v.x; s.y += v.y; s.z += v.z; s.w += v.w;
  }
  float4 xv = *(const float4*)(xb + (size_t)t * CD);
  const float inv = 1.0f / 25.0f;
  float4 o = {xv.x - s.x * inv, xv.y - s.y * inv, xv.z - s.z * inv, xv.w - s.w * inv};
  *(float4*)(out + (size_t)row * CD + d0) = o;
  ushort4 hv = {bf16r(o.x), bf16r(o.y), bf16r(o.z), bf16r(o.w)};
  *(ushort4*)(out2 + (size_t)row * CD + d0) = hv;
}

// ---------------- partial time-mean: grid (Bc, 8), coalesced ------------------------
__global__ __launch_bounds__(256) void k_meanp(const float* __restrict__ X,
                                               float* __restrict__ part) {
  int b = blockIdx.x, g = blockIdx.y, tid = threadIdx.x;
  const float* xb = X + (size_t)b * CT * CD + (size_t)g * 128 * CD;
  float a0 = 0.f, a1 = 0.f;
  for (int r = 0; r < 128; ++r) {
    a0 += xb[(size_t)r * CD + tid];
    a1 += xb[(size_t)r * CD + tid + 256];
  }
  part[((size_t)b * 8 + g) * CD + tid] = a0;
  part[((size_t)b * 8 + g) * CD + tid + 256] = a1;
}

// ---------------- final head: mean-combine + 2-layer MLP ----------------------------
__global__ __launch_bounds__(256) void k_headf(const float* __restrict__ part,
                                               const float* __restrict__ w1,
                                               const float* __restrict__ b1,
                                               const float* __restrict__ w2,
                                               const float* __restrict__ b2,
                                               float* __restrict__ out) {
  int b = blockIdx.x, tid = threadIdx.x;
  __shared__ float f[CD];
  __shared__ float hid[CFCH];
  for (int d = tid; d < CD; d += 256) {
    float s = 0.f;
#pragma unroll
    for (int g = 0; g < 8; ++g) s += part[((size_t)b * 8 + g) * CD + d];
    f[d] = s * (1.0f / CT);
  }
  __syncthreads();
  float a = b1[tid];
  for (int d = 0; d < CD; ++d) a += f[d] * w1[d * CFCH + tid];
  hid[tid] = fmaxf(a, 0.f);
  __syncthreads();
  if (tid < CNC) {
    float a2 = b2[tid];
    for (int j = 0; j < CFCH; ++j) a2 += hid[j] * w2[j * CNC + tid];
    out[b * CNC + tid] = a2;
  }
}

// =====================================================================================
extern "C" void kernel_launch(void* const* d_in, const int* in_sizes, int n_in,
                              void* d_out, int out_size, void* d_ws, size_t ws_size,
                              hipStream_t stream) {
  const float* x = (const float*)d_in[0];
  const float* emb_w = (const float*)d_in[1];
  const float* emb_g = (const float*)d_in[2];
  const float* emb_b = (const float*)d_in[3];
  const float* attn_w = (const float*)d_in[4];
  const float* attn_b = (const float*)d_in[5];
  const float* ln_g = (const float*)d_in[6];
  const float* ln_bb = (const float*)d_in[7];
  const float* fc1_w = (const float*)d_in[8];
  const float* fc1_b = (const float*)d_in[9];
  const float* fc2_w = (const float*)d_in[10];
  const float* fc2_b = (const float*)d_in[11];
  const float* hw1 = (const float*)d_in[12];
  const float* hb1 = (const float*)d_in[13];
  const float* hw2 = (const float*)d_in[14];
  const float* hb2 = (const float*)d_in[15];
  float* outp = (float*)d_out;

  // per-layer bf16 weights (ushorts): wq,wk,wv (contig => fused QKV), wo, w1, w2
  const size_t WQ = 262144ULL;                         // 512*512
  const size_t LW = 4 * WQ + 1048576ULL + 1048576ULL;  // 3,145,728 ushorts
  const size_t W2TOT = CL * LW;

  const size_t FIXED_B = W2TOT * 2                     // bf16 weights
                         + (size_t)CT * CD * 4         // postab
                         + 2 * (size_t)CB * CCH * 4    // sc,lg
                         + (size_t)CB * CT * 4         // corr
                         + 2 * (size_t)CB * CTOPK * 4  // wts,idxs
                         + (size_t)CB * 8 * CD * 4     // mean partials
                         + 4096;
  // per-b bytes: HP(2MB) + SA(2MB, doubles as Q/K-lo bf16 [T][1024]) + U0(1MB)
  //              + U1 [T][2048] bf16 (4MB)
  const size_t PERB = 2ULL * CT * CD * 4 + (size_t)CT * CD * 2 + (size_t)CT * 2048 * 2;
  int Bc = CB;
  while (Bc > 1) {
    if ((size_t)Bc * PERB + FIXED_B <= ws_size) break;
    Bc >>= 1;
  }
  const size_t CHF = (size_t)Bc * CT * CD;

  char* wsp = (char*)d_ws;
  float* P0 = (float*)wsp;     wsp += CHF * 4;
  float* P1 = (float*)wsp;     wsp += CHF * 4;
  ushort* U0 = (ushort*)wsp;   wsp += CHF * 2;            // h2 / agg-out / d2
  ushort* U1 = (ushort*)wsp;   wsp += (size_t)Bc * CT * 2048 * 2;  // qkv-hi / f2
  ushort* W2b = (ushort*)wsp;  wsp += W2TOT * 2;
  float* postab = (float*)wsp; wsp += (size_t)CT * CD * 4;
  float* scb = (float*)wsp;    wsp += (size_t)CB * CCH * 4;
  float* lgb = (float*)wsp;    wsp += (size_t)CB * CCH * 4;
  float* corrb = (float*)wsp;  wsp += (size_t)CB * CT * 4;
  float* wtb = (float*)wsp;    wsp += (size_t)CB * CTOPK * 4;
  int* idb = (int*)wsp;        wsp += (size_t)CB * CTOPK * 4;
  float* partb = (float*)wsp;  wsp += (size_t)CB * 8 * CD * 4;

  // ---- convert all weights to transposed bf16 [N][K], once per call ----
  for (int l = 0; l < CL; ++l) {
    ushort* wq2 = W2b + l * LW;      // [1536][512] fused QKV (q,k,v contiguous)
    ushort* wo2 = wq2 + 3 * WQ;
    ushort* w12 = wo2 + WQ;
    ushort* w22 = w12 + 1048576;
    for (int m = 0; m < 4; ++m)
      k_cvtw<<<dim3(CD / 32, CD / 32), 256, 0, stream>>>(
          attn_w + ((size_t)(l * 4 + m)) * CD * CD, wq2 + m * WQ, CD, CD);
    k_cvtw<<<dim3(CFFN / 32, CD / 32), 256, 0, stream>>>(
        fc1_w + (size_t)l * CD * CFFN, w12, CD, CFFN);
    k_cvtw<<<dim3(CD / 32, CFFN / 32), 256, 0, stream>>>(
        fc2_w + (size_t)l * CFFN * CD, w22, CFFN, CD);
  }

  k_scale<<<CB, 256, 0, stream>>>(x, scb, lgb);
  k_postab<<<CT, 512, 0, stream>>>(postab);

  for (int b0 = 0; b0 < CB; b0 += Bc) {
    const int Mc = Bc * CT;

    float* HP = P0;
    float* SA = P1;

    k_embed<<<Mc, 128, 0, stream>>>(x + (size_t)b0 * CT * CCH, scb + b0 * CCH,
                                    lgb + b0 * CCH, emb_w, postab, emb_g, emb_b,
                                    HP, U0);

    for (int l = 0; l < CL; ++l) {
      const float* bqkv = attn_b + (size_t)l * 4 * CD;  // q,k,v biases contiguous
      const float* bo = attn_b + (size_t)(l * 4 + 3) * CD;
      const float* g0 = ln_g + (size_t)(l * 2 + 0) * CD;
      const float* be0 = ln_bb + (size_t)(l * 2 + 0) * CD;
      const float* g1 = ln_g + (size_t)(l * 2 + 1) * CD;
      const float* be1 = ln_bb + (size_t)(l * 2 + 1) * CD;
      const float* B1 = fc1_b + (size_t)l * CFFN;
      const float* B2f = fc2_b + (size_t)l * CD;
      const ushort* wq2 = W2b + l * LW;
      const ushort* wo2 = wq2 + 3 * WQ;
      const ushort* w12 = wo2 + WQ;
      const ushort* w22 = w12 + 1048576;

      // Q/K lo-planes live in the currently-free SA buffer (overwritten by O-proj)
      ushort* U2 = (ushort*)SA;  // [Mc][1024]

      // fused QKV projection -> U1 hi [Mc][2048] (cols 0..1535); Q,K lo -> U2
      k_gemm3<6><<<dim3(1536 / 128, Mc / 128), 256, 0, stream>>>(
          U0, wq2, bqkv, nullptr, nullptr, U1, U2, CD, CD, 2048, CD);
      // corr = fold(Qhi Khi + Qhi Klo + Qlo Khi), one fused dispatch
      k_zero<<<(Bc * CT + 255) / 256, 256, 0, stream>>>(corrb, Bc * CT);
      k_corr3<<<dim3(CT / 128, CT / 128, Bc), 256, 0, stream>>>(U1, U2, corrb);
      k_topk<<<Bc, 1024, 0, stream>>>(corrb, wtb, idb);
      // delay aggregation (V = U1 cols 1024..1535) -> U0; O proj -> SA (fp32)
      k_agg<<<Mc, 128, 0, stream>>>(U1, wtb, idb, U0);
      k_gemm3<0><<<dim3(CD / 128, Mc / 128), 256, 0, stream>>>(
          U0, wo2, bo, nullptr, SA, nullptr, nullptr, CD, CD, CD, CD);
      // residual + LN -> HP; decomp -> SA (fp32 res) + U0 (bf16 d2)
      k_ln<1><<<Mc, 128, 0, stream>>>(HP, SA, g0, be0, HP);
      k_decomp<<<Mc, 128, 0, stream>>>(HP, SA, U0);
      // FFN single-pass: FC1 (GELU -> bf16 f2 = U1 [Mc][2048]), FC2 (+res) -> HP
      k_gemm3<1><<<dim3(CFFN / 128, Mc / 128), 256, 0, stream>>>(
          U0, w12, B1, nullptr, nullptr, U1, nullptr, CD, CD, CFFN, CD);
      k_gemm3<2><<<dim3(CD / 128, Mc / 128), 256, 0, stream>>>(
          U1, w22, B2f, SA, HP, nullptr, nullptr, CFFN, CFFN, CD, CFFN);
      // LN -> HP; decomp -> SA (next h fp32) + U0 (next h bf16); swap
      k_ln<0><<<Mc, 128, 0, stream>>>(HP, nullptr, g1, be1, HP);
      k_decomp<<<Mc, 128, 0, stream>>>(HP, SA, U0);
      float* t = HP;
      HP = SA;
      SA = t;
    }

    k_meanp<<<dim3(Bc, 8), 256, 0, stream>>>(HP, partb + (size_t)b0 * 8 * CD);
    k_headf<<<Bc, 256, 0, stream>>>(partb + (size_t)b0 * 8 * CD, hw1, hb1, hw2, hb2,
                                    outp + (size_t)b0 * CNC);
  }
}

// Round 12
// 3920.094 us; speedup vs baseline: 1.3750x; 1.0061x over previous
//
#include <hip/hip_runtime.h>
#include <math.h>

#define CB 64      // batch
#define CT 1024    // time
#define CCH 12     // channels
#define CD 512     // d_model
#define CL 2       // layers
#define CFFN 2048
#define CFCH 256
#define CNC 5
#define CTOPK 20
#define CEPS 1e-5f

typedef __attribute__((ext_vector_type(8))) short bfrag;
typedef __attribute__((ext_vector_type(4))) float ffrag;

__device__ inline ushort bf16r(float f) {
  unsigned u = __float_as_uint(f);
  unsigned r = (u + 0x7FFFu + ((u >> 16) & 1u)) >> 16;
  return (ushort)r;
}
__device__ inline float bf16f(ushort h) { return __uint_as_float(((unsigned)h) << 16); }

// async 16B global->LDS (lds dest = wave-uniform base + lane*16)
__device__ __forceinline__ void gld16(const ushort* g, ushort* l) {
  __builtin_amdgcn_global_load_lds((__attribute__((address_space(1))) void*)g,
                                   (__attribute__((address_space(3))) void*)l,
                                   16, 0, 0);
}

// ---------------- mean-abs scaler ----------------
__global__ __launch_bounds__(256) void k_scale(const float* __restrict__ x,
                                               float* __restrict__ sc,
                                               float* __restrict__ lg) {
  int b = blockIdx.x, tid = threadIdx.x;
  float acc[CCH];
#pragma unroll
  for (int c = 0; c < CCH; ++c) acc[c] = 0.f;
  const float* xb = x + (size_t)b * CT * CCH;
  for (int t = tid; t < CT; t += 256) {
    const float* row = xb + t * CCH;
#pragma unroll
    for (int c = 0; c < CCH; ++c) acc[c] += fabsf(row[c]);
  }
  __shared__ float red[256][CCH];
#pragma unroll
  for (int c = 0; c < CCH; ++c) red[tid][c] = acc[c];
  __syncthreads();
  for (int off = 128; off > 0; off >>= 1) {
    if (tid < off) {
#pragma unroll
      for (int c = 0; c < CCH; ++c) red[tid][c] += red[tid + off][c];
    }
    __syncthreads();
  }
  if (tid < CCH) {
    float s = fmaxf(red[0][tid] * (1.0f / CT), 1e-10f);
    sc[b * CCH + tid] = s;
    lg[b * CCH + tid] = logf(s);
  }
}

// ---------------- sinusoidal position table (f64, matches np) ----------------
__global__ __launch_bounds__(512) void k_postab(float* __restrict__ pos) {
  int t = blockIdx.x;
  int d = threadIdx.x;
  double v;
  if (d < 256) {
    double w = pow(10000.0, -((double)d) / 256.0);
    v = sin((double)t * w);
  } else {
    double w = pow(10000.0, -((double)(d - 256)) / 256.0);
    v = cos((double)t * w);
  }
  pos[(size_t)t * CD + d] = (float)v;
}

// ---------------- embedding + LN fused; writes fp32 h AND bf16 h2 -------------------
__global__ __launch_bounds__(128) void k_embed(const float* __restrict__ x,
                                               const float* __restrict__ sc,
                                               const float* __restrict__ lg,
                                               const float* __restrict__ W,
                                               const float* __restrict__ postab,
                                               const float* __restrict__ g,
                                               const float* __restrict__ beta,
                                               float* __restrict__ h,
                                               ushort* __restrict__ h2) {
  int row = blockIdx.x;  // local: b*T + t
  int b = row >> 10, t = row & 1023;
  int tid = threadIdx.x;
  __shared__ float xs[CCH], ls[CCH];
  if (tid < CCH) {
    float s = sc[b * CCH + tid];
    xs[tid] = x[(size_t)row * CCH + tid] / s;
    ls[tid] = lg[b * CCH + tid];
  }
  __syncthreads();
  int d0 = tid * 4;
  float4 p = *(const float4*)(postab + (size_t)t * CD + d0);
  float v0 = p.x, v1 = p.y, v2 = p.z, v3 = p.w;
#pragma unroll
  for (int c = 0; c < CCH; ++c) {
    float xc = xs[c], lc = ls[c];
    float4 w0 = *(const float4*)(W + (size_t)c * CD + d0);
    float4 w1 = *(const float4*)(W + (size_t)(24 + c) * CD + d0);
    v0 += xc * w0.x + lc * w1.x;
    v1 += xc * w0.y + lc * w1.y;
    v2 += xc * w0.z + lc * w1.z;
    v3 += xc * w0.w + lc * w1.w;
  }
  float s1 = v0 + v1 + v2 + v3;
  float s2 = v0 * v0 + v1 * v1 + v2 * v2 + v3 * v3;
  for (int off = 32; off > 0; off >>= 1) {
    s1 += __shfl_down(s1, off);
    s2 += __shfl_down(s2, off);
  }
  __shared__ float ws1[2], ws2[2], mv[2];
  int wid = tid >> 6, lane = tid & 63;
  if (lane == 0) { ws1[wid] = s1; ws2[wid] = s2; }
  __syncthreads();
  if (tid == 0) {
    float S1 = ws1[0] + ws1[1], S2 = ws2[0] + ws2[1];
    float mu = S1 * (1.0f / CD);
    float var = S2 * (1.0f / CD) - mu * mu;
    mv[0] = mu;
    mv[1] = 1.0f / sqrtf(var + CEPS);
  }
  __syncthreads();
  float mu = mv[0], ri = mv[1];
  float4 gg = *(const float4*)(g + d0);
  float4 bb = *(const float4*)(beta + d0);
  float4 o;
  o.x = (v0 - mu) * ri * gg.x + bb.x;
  o.y = (v1 - mu) * ri * gg.y + bb.y;
  o.z = (v2 - mu) * ri * gg.z + bb.z;
  o.w = (v3 - mu) * ri * gg.w + bb.w;
  *(float4*)(h + (size_t)row * CD + d0) = o;
  ushort4 hv = {bf16r(o.x), bf16r(o.y), bf16r(o.z), bf16r(o.w)};
  *(ushort4*)(h2 + (size_t)row * CD + d0) = hv;
}

// ---------------- weight convert+transpose: W[K][N] fp32 -> W2[N][K] bf16 -----------
__global__ __launch_bounds__(256) void k_cvtw(const float* __restrict__ W,
                                              ushort* __restrict__ W2,
                                              int K, int N) {
  __shared__ float tile[32][33];
  int tx = threadIdx.x & 31, ty = threadIdx.x >> 5;  // ty 0..7
  int n0 = blockIdx.x * 32, k0 = blockIdx.y * 32;
#pragma unroll
  for (int r = 0; r < 4; ++r)
    tile[ty * 4 + r][tx] = W[(size_t)(k0 + ty * 4 + r) * N + n0 + tx];
  __syncthreads();
#pragma unroll
  for (int r = 0; r < 4; ++r) {
    int nl = ty * 4 + r, kl = tx;
    W2[(size_t)(n0 + nl) * K + k0 + kl] = bf16r(tile[kl][nl]);
  }
}

// ---------------- zero helper ----------------
__global__ __launch_bounds__(256) void k_zero(float* __restrict__ p, int n) {
  int i = blockIdx.x * 256 + threadIdx.x;
  if (i < n) p[i] = 0.f;
}

// ---------------- bf16 MFMA GEMM, 128x128 tile, BK=32, double-buffered pipeline -----
// A: [M][lda] bf16 k-contig rows; W: [N][ldb] bf16 k-contig rows.
// LDS chunk swizzle: chunk q of row r at slot q^((r>>2)&3) -> 2-way bank access (free).
// (Swizzle is a pure LDS slot permutation — bit-identical results vs any other.)
// Pipeline: prefetch distance 2; per-iter wait `s_waitcnt vmcnt(4)`.
// EPI: 0=bias->fp32  1=bias+GELU->bf16  2=bias+residual->fp32
//      6=bias->bf16 hi (Cs, ldc) + lo for cols<1024 (Cs2, ld 1024) [QKV]
template <int EPI>
__global__ __launch_bounds__(256) void k_gemm3(const ushort* __restrict__ A,
                                               const ushort* __restrict__ W,
                                               const float* __restrict__ bias,
                                               const float* __restrict__ R,
                                               float* __restrict__ Cf,
                                               ushort* __restrict__ Cs,
                                               ushort* __restrict__ Cs2,
                                               int lda, int ldb, int ldc, int K) {
  __shared__ ushort AhS[2][128 * 32];
  __shared__ ushort BhS[2][128 * 32];
  int tid = threadIdx.x;
  int n0 = blockIdx.x * 128, m0 = blockIdx.y * 128;
  int wid = __builtin_amdgcn_readfirstlane(tid >> 6);
  int lane = tid & 63;
  int lr = lane >> 2;                              // 0..15: row in a 16-row gld16 group
  int lc = ((lane & 3) ^ ((lr >> 2) & 3)) * 8;     // swizzled source chunk (ushorts)
  int wm = wid >> 1, wn = wid & 1;
  int mOff = wm * 64, nOff = wn * 64;
  int quad = lane >> 4, l16 = lane & 15;

  const ushort* pA = A + (size_t)(m0 + wid * 32 + lr) * lda + lc;
  const ushort* pB = W + (size_t)(n0 + wid * 32 + lr) * ldb + lc;
  const int NK = K >> 5;

  ffrag acc[4][4];
#pragma unroll
  for (int i = 0; i < 4; ++i)
#pragma unroll
    for (int j = 0; j < 4; ++j) acc[i][j] = (ffrag)(0.f);

#define ISSUE(t, buf)                                                        \
  {                                                                          \
    int kk = (t) << 5;                                                       \
    ushort* lA = &AhS[buf][(wid * 32) * 32];                                 \
    ushort* lB = &BhS[buf][(wid * 32) * 32];                                 \
    gld16(pA + kk, lA);                                                      \
    gld16(pA + (size_t)16 * lda + kk, lA + 16 * 32);                         \
    gld16(pB + kk, lB);                                                      \
    gld16(pB + (size_t)16 * ldb + kk, lB + 16 * 32);                         \
  }

  ISSUE(0, 0);
  ISSUE(1, 1);
  for (int k = 0; k < NK; ++k) {
    if (k + 1 < NK) {
      asm volatile("s_waitcnt vmcnt(4)\n\ts_barrier" ::: "memory");
    } else {
      asm volatile("s_waitcnt vmcnt(0)\n\ts_barrier" ::: "memory");
    }
    int buf = k & 1;
    bfrag ah[4], bh[4];
#pragma unroll
    for (int i = 0; i < 4; ++i) {
      int row = mOff + i * 16 + l16;
      ah[i] = *(const bfrag*)&AhS[buf][row * 32 + (quad ^ ((row >> 2) & 3)) * 8];
    }
#pragma unroll
    for (int j = 0; j < 4; ++j) {
      int row = nOff + j * 16 + l16;
      bh[j] = *(const bfrag*)&BhS[buf][row * 32 + (quad ^ ((row >> 2) & 3)) * 8];
    }
#pragma unroll
    for (int i = 0; i < 4; ++i)
#pragma unroll
      for (int j = 0; j < 4; ++j)
        acc[i][j] = __builtin_amdgcn_mfma_f32_16x16x32_bf16(ah[i], bh[j], acc[i][j], 0, 0, 0);
    asm volatile("s_barrier" ::: "memory");
    if (k + 2 < NK) ISSUE(k + 2, buf);
  }
#undef ISSUE

  // C tile layout: col = lane&15, row = quad*4 + reg (verified R3-R10)
#pragma unroll
  for (int j = 0; j < 4; ++j) {
    int col = n0 + nOff + j * 16 + l16;
    float bcol = bias[col];
#pragma unroll
    for (int i = 0; i < 4; ++i) {
      int rowb = m0 + mOff + i * 16 + quad * 4;
#pragma unroll
      for (int r = 0; r < 4; ++r) {
        int row = rowb + r;
        float vv = acc[i][j][r] + bcol;
        if (EPI == 1) vv = 0.5f * vv * (1.0f + erff(vv * 0.7071067811865475f));
        if (EPI == 2) vv += R[(size_t)row * ldc + col];
        if (EPI == 1) {
          Cs[(size_t)row * ldc + col] = bf16r(vv);
        } else if (EPI == 6) {
          ushort hi = bf16r(vv);
          Cs[(size_t)row * ldc + col] = hi;
          if (col < 1024)
            Cs2[(size_t)row * 1024 + col] = bf16r(vv - bf16f(hi));
        } else {
          Cf[(size_t)row * ldc + col] = vv;
        }
      }
    }
  }
}

// ---------------- fused 3-term correlation fold (R10 accumulation order) ------------
// corr[z,(m-n)%T] += (1/512) * sum_d [Qhi*Khi + Qhi*Klo + Qlo*Khi]
// Interleaved per 32-k chunk (hh, hl, lh) — DO NOT REORDER (tie-sensitive, R11).
// Qhi/Khi rows in Hi (ld 2048, K at col 512); Qlo/Klo in Lo (ld 1024, Klo at 512).
__global__ __launch_bounds__(256) void k_corr3(const ushort* __restrict__ Hi,
                                               const ushort* __restrict__ Lo,
                                               float* __restrict__ corrb) {
  __shared__ ushort AhS[2][128 * 32], AlS[2][128 * 32];
  __shared__ ushort BhS[2][128 * 32], BlS[2][128 * 32];
  int tid = threadIdx.x;
  int n0 = blockIdx.x * 128, m0 = blockIdx.y * 128;
  int z = blockIdx.z;
  int wid = __builtin_amdgcn_readfirstlane(tid >> 6);
  int lane = tid & 63;
  int lr = lane >> 2;
  int lc = ((lane & 3) ^ ((lr >> 2) & 3)) * 8;
  int wm = wid >> 1, wn = wid & 1;
  int mOff = wm * 64, nOff = wn * 64;
  int quad = lane >> 4, l16 = lane & 15;

  const ushort* Hz = Hi + (size_t)z * CT * 2048;
  const ushort* Lz = Lo + (size_t)z * CT * 1024;
  const ushort* pAh = Hz + (size_t)(m0 + wid * 32 + lr) * 2048 + lc;
  const ushort* pAl = Lz + (size_t)(m0 + wid * 32 + lr) * 1024 + lc;
  const ushort* pBh = Hz + 512 + (size_t)(n0 + wid * 32 + lr) * 2048 + lc;
  const ushort* pBl = Lz + 512 + (size_t)(n0 + wid * 32 + lr) * 1024 + lc;
  const int NK = 16;  // 512/32

  ffrag acc[4][4];
#pragma unroll
  for (int i = 0; i < 4; ++i)
#pragma unroll
    for (int j = 0; j < 4; ++j) acc[i][j] = (ffrag)(0.f);

#define ISSUE3(t, buf)                                                       \
  {                                                                          \
    int kk = (t) << 5;                                                       \
    int base = (wid * 32) * 32;                                              \
    gld16(pAh + kk, &AhS[buf][base]);                                        \
    gld16(pAh + (size_t)16 * 2048 + kk, &AhS[buf][base + 16 * 32]);          \
    gld16(pAl + kk, &AlS[buf][base]);                                        \
    gld16(pAl + (size_t)16 * 1024 + kk, &AlS[buf][base + 16 * 32]);          \
    gld16(pBh + kk, &BhS[buf][base]);                                        \
    gld16(pBh + (size_t)16 * 2048 + kk, &BhS[buf][base + 16 * 32]);          \
    gld16(pBl + kk, &BlS[buf][base]);                                        \
    gld16(pBl + (size_t)16 * 1024 + kk, &BlS[buf][base + 16 * 32]);          \
  }

  ISSUE3(0, 0);
  ISSUE3(1, 1);
  for (int k = 0; k < NK; ++k) {
    if (k + 1 < NK) {
      asm volatile("s_waitcnt vmcnt(8)\n\ts_barrier" ::: "memory");
    } else {
      asm volatile("s_waitcnt vmcnt(0)\n\ts_barrier" ::: "memory");
    }
    int buf = k & 1;
    bfrag ah[4], al[4], bh[4], bl[4];
#pragma unroll
    for (int i = 0; i < 4; ++i) {
      int row = mOff + i * 16 + l16;
      int off = row * 32 + (quad ^ ((row >> 2) & 3)) * 8;
      ah[i] = *(const bfrag*)&AhS[buf][off];
      al[i] = *(const bfrag*)&AlS[buf][off];
    }
#pragma unroll
    for (int j = 0; j < 4; ++j) {
      int row = nOff + j * 16 + l16;
      int off = row * 32 + (quad ^ ((row >> 2) & 3)) * 8;
      bh[j] = *(const bfrag*)&BhS[buf][off];
      bl[j] = *(const bfrag*)&BlS[buf][off];
    }
#pragma unroll
    for (int i = 0; i < 4; ++i)
#pragma unroll
      for (int j = 0; j < 4; ++j) {
        acc[i][j] = __builtin_amdgcn_mfma_f32_16x16x32_bf16(ah[i], bh[j], acc[i][j], 0, 0, 0);
        acc[i][j] = __builtin_amdgcn_mfma_f32_16x16x32_bf16(ah[i], bl[j], acc[i][j], 0, 0, 0);
        acc[i][j] = __builtin_amdgcn_mfma_f32_16x16x32_bf16(al[i], bh[j], acc[i][j], 0, 0, 0);
      }
    asm volatile("s_barrier" ::: "memory");
    if (k + 2 < NK) ISSUE3(k + 2, buf);
  }
#undef ISSUE3

  // diagonal fold via LDS bins
  __shared__ float bins[256];
  bins[tid] = 0.f;
  __syncthreads();
  int base = 127 + mOff + quad * 4 - nOff - l16;
#pragma unroll
  for (int dd = -3; dd <= 3; ++dd) {
#pragma unroll
    for (int r = 0; r < 4; ++r) {
      float s = 0.f;
#pragma unroll
      for (int i = 0; i < 4; ++i) {
        int j = i - dd;
        if (j >= 0 && j < 4) s += acc[i][j][r];
      }
      atomicAdd(&bins[base + dd * 16 + r], s);
    }
  }
  __syncthreads();
  if (tid < 255) {
    float v = bins[tid];
    if (v != 0.f) {
      int diag = (m0 - n0 + tid - 127 + 2048) & (CT - 1);
      atomicAdd(&corrb[(size_t)z * CT + diag], v * (1.0f / 512.0f));
    }
  }
}

// ---------------- top-k (k=20) + softmax, 1024 threads ----------------
__global__ __launch_bounds__(1024) void k_topk(const float* __restrict__ corrb,
                                               float* __restrict__ wts,
                                               int* __restrict__ idxs) {
  int b = blockIdx.x, tid = threadIdx.x;
  float cur = corrb[(size_t)b * CT + tid];
  __shared__ float swv[16];
  __shared__ int swi[16];
  __shared__ float selv[CTOPK];
  __shared__ int seli[CTOPK];
  int wid = tid >> 6, lane = tid & 63;
  for (int k = 0; k < CTOPK; ++k) {
    float bv = cur;
    int bi = tid;
#pragma unroll
    for (int off = 32; off > 0; off >>= 1) {
      float ov = __shfl_down(bv, off);
      int oi = __shfl_down(bi, off);
      if (ov > bv || (ov == bv && oi < bi)) { bv = ov; bi = oi; }
    }
    if (lane == 0) { swv[wid] = bv; swi[wid] = bi; }
    __syncthreads();
    if (tid == 0) {
      float mv = swv[0];
      int mi = swi[0];
      for (int q = 1; q < 16; ++q) {
        if (swv[q] > mv || (swv[q] == mv && swi[q] < mi)) { mv = swv[q]; mi = swi[q]; }
      }
      selv[k] = mv;
      seli[k] = mi;
    }
    __syncthreads();
    if (tid == seli[k]) cur = -INFINITY;
    __syncthreads();
  }
  if (tid == 0) {
    float mx = selv[0], sum = 0.f, e[CTOPK];
    for (int k = 0; k < CTOPK; ++k) {
      e[k] = expf(selv[k] - mx);
      sum += e[k];
    }
    float inv = 1.0f / sum;
    for (int k = 0; k < CTOPK; ++k) {
      wts[b * CTOPK + k] = e[k] * inv;
      idxs[b * CTOPK + k] = seli[k];
    }
  }
}

// ---------------- delay aggregation: bf16 V (cols 1024.. in U1, ld 2048) ------------
__global__ __launch_bounds__(128) void k_agg(const ushort* __restrict__ qkv,
                                             const float* __restrict__ wts,
                                             const int* __restrict__ idxs,
                                             ushort* __restrict__ out2) {
  int nb = gridDim.x;
  int blk = blockIdx.x;
  int row = (blk & 7) * (nb >> 3) + (blk >> 3);
  int b = row >> 10, t = row & 1023;
  int d0 = threadIdx.x * 4;
  const ushort* Vb = qkv + (size_t)b * CT * 2048 + 1024;
  float4 acc = {0.f, 0.f, 0.f, 0.f};
#pragma unroll
  for (int k = 0; k < CTOPK; ++k) {
    float w = wts[b * CTOPK + k];
    int r = t + idxs[b * CTOPK + k];
    if (r >= CT) r -= CT;
    ushort4 v = *(const ushort4*)(Vb + (size_t)r * 2048 + d0);
    acc.x += w * bf16f(v.x);
    acc.y += w * bf16f(v.y);
    acc.z += w * bf16f(v.z);
    acc.w += w * bf16f(v.w);
  }
  ushort4 hv = {bf16r(acc.x), bf16r(acc.y), bf16r(acc.z), bf16r(acc.w)};
  *(ushort4*)(out2 + (size_t)row * CD + d0) = hv;
}

// ---------------- LayerNorm (optional residual add) ----------------
template <int ADD>
__global__ __launch_bounds__(128) void k_ln(const float* __restrict__ X,
                                            const float* __restrict__ Rr,
                                            const float* __restrict__ g,
                                            const float* __restrict__ beta,
                                            float* __restrict__ out) {
  int row = blockIdx.x, tid = threadIdx.x;
  int d0 = tid * 4;
  float4 v = *(const float4*)(X + (size_t)row * CD + d0);
  if (ADD) {
    float4 r = *(const float4*)(Rr + (size_t)row * CD + d0);
    v.x += r.x; v.y += r.y; v.z += r.z; v.w += r.w;
  }
  float s1 = v.x + v.y + v.z + v.w;
  float s2 = v.x * v.x + v.y * v.y + v.z * v.z + v.w * v.w;
  for (int off = 32; off > 0; off >>= 1) {
    s1 += __shfl_down(s1, off);
    s2 += __shfl_down(s2, off);
  }
  __shared__ float ws1[2], ws2[2], mv[2];
  int wid = tid >> 6, lane = tid & 63;
  if (lane == 0) { ws1[wid] = s1; ws2[wid] = s2; }
  __syncthreads();
  if (tid == 0) {
    float S1 = ws1[0] + ws1[1], S2 = ws2[0] + ws2[1];
    float mu = S1 * (1.0f / CD);
    float var = S2 * (1.0f / CD) - mu * mu;
    mv[0] = mu;
    mv[1] = 1.0f / sqrtf(var + CEPS);
  }
  __syncthreads();
  float mu = mv[0], ri = mv[1];
  float4 gg = *(const float4*)(g + d0);
  float4 bb = *(const float4*)(beta + d0);
  float4 o;
  o.x = (v.x - mu) * ri * gg.x + bb.x;
  o.y = (v.y - mu) * ri * gg.y + bb.y;
  o.z = (v.z - mu) * ri * gg.z + bb.z;
  o.w = (v.w - mu) * ri * gg.w + bb.w;
  *(float4*)(out + (size_t)row * CD + d0) = o;
}

// ---------------- series decomp: fp32 out + bf16 out; XCD-swizzled ------------------
__global__ __launch_bounds__(128) void k_decomp(const float* __restrict__ X,
                                                float* __restrict__ out,
                                                ushort* __restrict__ out2) {
  int nb = gridDim.x;
  int blk = blockIdx.x;
  int row = (blk & 7) * (nb >> 3) + (blk >> 3);
  int b = row >> 10, t = row & 1023;
  int d0 = threadIdx.x * 4;
  const float* xb = X + (size_t)b * CT * CD + d0;
  float4 s = {0.f, 0.f, 0.f, 0.f};
#pragma unroll
  for (int j = -12; j <= 12; ++j) {
    int tt = t + j;
    tt = tt < 0 ? 0 : (tt > CT - 1 ? CT - 1 : tt);
    float4 v = *(const float4*)(xb + (size_t)tt * CD);
    s.x += v.x; s.y += v.y; s.z += v.z; s.w += v.w;
  }
  float4 xv = *(const float4*)(xb + (size_t)t * CD);
  const float inv = 1.0f / 25.0f;
  float4 o = {xv.x - s.x * inv, xv.y - s.y * inv, xv.z - s.z * inv, xv.w - s.w * inv};
  *(float4*)(out + (size_t)row * CD + d0) = o;
  ushort4 hv = {bf16r(o.x), bf16r(o.y), bf16r(o.z), bf16r(o.w)};
  *(ushort4*)(out2 + (size_t)row * CD + d0) = hv;
}

// ---------------- partial time-mean: grid (Bc, 8), coalesced ------------------------
__global__ __launch_bounds__(256) void k_meanp(const float* __restrict__ X,
                                               float* __restrict__ part) {
  int b = blockIdx.x, g = blockIdx.y, tid = threadIdx.x;
  const float* xb = X + (size_t)b * CT * CD + (size_t)g * 128 * CD;
  float a0 = 0.f, a1 = 0.f;
  for (int r = 0; r < 128; ++r) {
    a0 += xb[(size_t)r * CD + tid];
    a1 += xb[(size_t)r * CD + tid + 256];
  }
  part[((size_t)b * 8 + g) * CD + tid] = a0;
  part[((size_t)b * 8 + g) * CD + tid + 256] = a1;
}

// ---------------- final head: mean-combine + 2-layer MLP ----------------------------
__global__ __launch_bounds__(256) void k_headf(const float* __restrict__ part,
                                               const float* __restrict__ w1,
                                               const float* __restrict__ b1,
                                               const float* __restrict__ w2,
                                               const float* __restrict__ b2,
                                               float* __restrict__ out) {
  int b = blockIdx.x, tid = threadIdx.x;
  __shared__ float f[CD];
  __shared__ float hid[CFCH];
  for (int d = tid; d < CD; d += 256) {
    float s = 0.f;
#pragma unroll
    for (int g = 0; g < 8; ++g) s += part[((size_t)b * 8 + g) * CD + d];
    f[d] = s * (1.0f / CT);
  }
  __syncthreads();
  float a = b1[tid];
  for (int d = 0; d < CD; ++d) a += f[d] * w1[d * CFCH + tid];
  hid[tid] = fmaxf(a, 0.f);
  __syncthreads();
  if (tid < CNC) {
    float a2 = b2[tid];
    for (int j = 0; j < CFCH; ++j) a2 += hid[j] * w2[j * CNC + tid];
    out[b * CNC + tid] = a2;
  }
}

// =====================================================================================
extern "C" void kernel_launch(void* const* d_in, const int* in_sizes, int n_in,
                              void* d_out, int out_size, void* d_ws, size_t ws_size,
                              hipStream_t stream) {
  const float* x = (const float*)d_in[0];
  const float* emb_w = (const float*)d_in[1];
  const float* emb_g = (const float*)d_in[2];
  const float* emb_b = (const float*)d_in[3];
  const float* attn_w = (const float*)d_in[4];
  const float* attn_b = (const float*)d_in[5];
  const float* ln_g = (const float*)d_in[6];
  const float* ln_bb = (const float*)d_in[7];
  const float* fc1_w = (const float*)d_in[8];
  const float* fc1_b = (const float*)d_in[9];
  const float* fc2_w = (const float*)d_in[10];
  const float* fc2_b = (const float*)d_in[11];
  const float* hw1 = (const float*)d_in[12];
  const float* hb1 = (const float*)d_in[13];
  const float* hw2 = (const float*)d_in[14];
  const float* hb2 = (const float*)d_in[15];
  float* outp = (float*)d_out;

  // per-layer bf16 weights (ushorts): wq,wk,wv (contig => fused QKV), wo, w1, w2
  const size_t WQ = 262144ULL;                         // 512*512
  const size_t LW = 4 * WQ + 1048576ULL + 1048576ULL;  // 3,145,728 ushorts
  const size_t W2TOT = CL * LW;

  const size_t FIXED_B = W2TOT * 2                     // bf16 weights
                         + (size_t)CT * CD * 4         // postab
                         + 2 * (size_t)CB * CCH * 4    // sc,lg
                         + (size_t)CB * CT * 4         // corr
                         + 2 * (size_t)CB * CTOPK * 4  // wts,idxs
                         + (size_t)CB * 8 * CD * 4     // mean partials
                         + 4096;
  // per-b bytes: HP(2MB) + SA(2MB, doubles as Q/K-lo bf16 [T][1024]) + U0(1MB)
  //              + U1 [T][2048] bf16 (4MB)
  const size_t PERB = 2ULL * CT * CD * 4 + (size_t)CT * CD * 2 + (size_t)CT * 2048 * 2;
  int Bc = CB;
  while (Bc > 1) {
    if ((size_t)Bc * PERB + FIXED_B <= ws_size) break;
    Bc >>= 1;
  }
  const size_t CHF = (size_t)Bc * CT * CD;

  char* wsp = (char*)d_ws;
  float* P0 = (float*)wsp;     wsp += CHF * 4;
  float* P1 = (float*)wsp;     wsp += CHF * 4;
  ushort* U0 = (ushort*)wsp;   wsp += CHF * 2;            // h2 / agg-out / d2
  ushort* U1 = (ushort*)wsp;   wsp += (size_t)Bc * CT * 2048 * 2;  // qkv-hi / f2
  ushort* W2b = (ushort*)wsp;  wsp += W2TOT * 2;
  float* postab = (float*)wsp; wsp += (size_t)CT * CD * 4;
  float* scb = (float*)wsp;    wsp += (size_t)CB * CCH * 4;
  float* lgb = (float*)wsp;    wsp += (size_t)CB * CCH * 4;
  float* corrb = (float*)wsp;  wsp += (size_t)CB * CT * 4;
  float* wtb = (float*)wsp;    wsp += (size_t)CB * CTOPK * 4;
  int* idb = (int*)wsp;        wsp += (size_t)CB * CTOPK * 4;
  float* partb = (float*)wsp;  wsp += (size_t)CB * 8 * CD * 4;

  // ---- convert all weights to transposed bf16 [N][K], once per call ----
  for (int l = 0; l < CL; ++l) {
    ushort* wq2 = W2b + l * LW;      // [1536][512] fused QKV (q,k,v contiguous)
    ushort* wo2 = wq2 + 3 * WQ;
    ushort* w12 = wo2 + WQ;
    ushort* w22 = w12 + 1048576;
    for (int m = 0; m < 4; ++m)
      k_cvtw<<<dim3(CD / 32, CD / 32), 256, 0, stream>>>(
          attn_w + ((size_t)(l * 4 + m)) * CD * CD, wq2 + m * WQ, CD, CD);
    k_cvtw<<<dim3(CFFN / 32, CD / 32), 256, 0, stream>>>(
        fc1_w + (size_t)l * CD * CFFN, w12, CD, CFFN);
    k_cvtw<<<dim3(CD / 32, CFFN / 32), 256, 0, stream>>>(
        fc2_w + (size_t)l * CFFN * CD, w22, CFFN, CD);
  }

  k_scale<<<CB, 256, 0, stream>>>(x, scb, lgb);
  k_postab<<<CT, 512, 0, stream>>>(postab);

  for (int b0 = 0; b0 < CB; b0 += Bc) {
    const int Mc = Bc * CT;

    float* HP = P0;
    float* SA = P1;

    k_embed<<<Mc, 128, 0, stream>>>(x + (size_t)b0 * CT * CCH, scb + b0 * CCH,
                                    lgb + b0 * CCH, emb_w, postab, emb_g, emb_b,
                                    HP, U0);

    for (int l = 0; l < CL; ++l) {
      const float* bqkv = attn_b + (size_t)l * 4 * CD;  // q,k,v biases contiguous
      const float* bo = attn_b + (size_t)(l * 4 + 3) * CD;
      const float* g0 = ln_g + (size_t)(l * 2 + 0) * CD;
      const float* be0 = ln_bb + (size_t)(l * 2 + 0) * CD;
      const float* g1 = ln_g + (size_t)(l * 2 + 1) * CD;
      const float* be1 = ln_bb + (size_t)(l * 2 + 1) * CD;
      const float* B1 = fc1_b + (size_t)l * CFFN;
      const float* B2f = fc2_b + (size_t)l * CD;
      const ushort* wq2 = W2b + l * LW;
      const ushort* wo2 = wq2 + 3 * WQ;
      const ushort* w12 = wo2 + WQ;
      const ushort* w22 = w12 + 1048576;

      // Q/K lo-planes live in the currently-free SA buffer (overwritten by O-proj)
      ushort* U2 = (ushort*)SA;  // [Mc][1024]

      // fused QKV projection -> U1 hi [Mc][2048] (cols 0..1535); Q,K lo -> U2
      k_gemm3<6><<<dim3(1536 / 128, Mc / 128), 256, 0, stream>>>(
          U0, wq2, bqkv, nullptr, nullptr, U1, U2, CD, CD, 2048, CD);
      // corr = fold(Qhi Khi + Qhi Klo + Qlo Khi), one fused dispatch (R10 order)
      k_zero<<<(Bc * CT + 255) / 256, 256, 0, stream>>>(corrb, Bc * CT);
      k_corr3<<<dim3(CT / 128, CT / 128, Bc), 256, 0, stream>>>(U1, U2, corrb);
      k_topk<<<Bc, 1024, 0, stream>>>(corrb, wtb, idb);
      // delay aggregation (V = U1 cols 1024..1535) -> U0; O proj (+residual HP) -> SA
      k_agg<<<Mc, 128, 0, stream>>>(U1, wtb, idb, U0);
      k_gemm3<2><<<dim3(CD / 128, Mc / 128), 256, 0, stream>>>(
          U0, wo2, bo, HP, SA, nullptr, nullptr, CD, CD, CD, CD);
      // LN(SA) -> HP; decomp -> SA (fp32 res) + U0 (bf16 d2)
      k_ln<0><<<Mc, 128, 0, stream>>>(SA, nullptr, g0, be0, HP);
      k_decomp<<<Mc, 128, 0, stream>>>(HP, SA, U0);
      // FFN single-pass: FC1 (GELU -> bf16 f2 = U1 [Mc][2048]), FC2 (+res) -> HP
      k_gemm3<1><<<dim3(CFFN / 128, Mc / 128), 256, 0, stream>>>(
          U0, w12, B1, nullptr, nullptr, U1, nullptr, CD, CD, CFFN, CD);
      k_gemm3<2><<<dim3(CD / 128, Mc / 128), 256, 0, stream>>>(
          U1, w22, B2f, SA, HP, nullptr, nullptr, CFFN, CFFN, CD, CFFN);
      // LN -> HP; decomp -> SA (next h fp32) + U0 (next h bf16); swap
      k_ln<0><<<Mc, 128, 0, stream>>>(HP, nullptr, g1, be1, HP);
      k_decomp<<<Mc, 128, 0, stream>>>(HP, SA, U0);
      float* t = HP;
      HP = SA;
      SA = t;
    }

    k_meanp<<<dim3(Bc, 8), 256, 0, stream>>>(HP, partb + (size_t)b0 * 8 * CD);
    k_headf<<<Bc, 256, 0, stream>>>(partb + (size_t)b0 * 8 * CD, hw1, hb1, hw2, hb2,
                                    outp + (size_t)b0 * CNC);
  }
}